// Round 10
// baseline (264.042 us; speedup 1.0000x reference)
//
#include <hip/hip_runtime.h>
#include <hip/hip_bf16.h>
#include <math.h>

#define BB   2
#define SS   2048
#define HIDN 2048
#define HH   16
#define HKVV 4
#define DD   128
#define NCH  32   // S/CHUNK
#define CHK  64
#define NBLK 32   // S/WIN

typedef __attribute__((ext_vector_type(8))) short bf16x8;
typedef __attribute__((ext_vector_type(4))) float f32x4;

__device__ __forceinline__ short f2bf(float x)
{
  __hip_bfloat16 h = __float2bfloat16(x);
  return *(short*)&h;
}
__device__ __forceinline__ float bf2f(short x)
{
  return __uint_as_float(((uint)(ushort)x) << 16);
}

__device__ __forceinline__ void gld_lds16(const short* g, short* lds)
{
  __builtin_amdgcn_global_load_lds(
      (const __attribute__((address_space(1))) void*)g,
      (__attribute__((address_space(3))) void*)lds, 16, 0, 0);
}

// swizzled LDS helpers: byte ^= ((row&7)<<4) within each 8-row stripe
__device__ __forceinline__ bf16x8 ldsA(const short* base, int row, int rs, int ks)
{
  int byte = (row * rs + ks) * 2;
  byte ^= ((row & 7) << 4);
  __builtin_assume((byte & 15) == 0);
  return *(const bf16x8*)((const char*)base + byte);
}
__device__ __forceinline__ void lds_w16_swz(short* base, int row, int rs, int ks, short v)
{
  int byte = (row * rs + ks) * 2;
  byte ^= ((row & 7) << 4);
  *(short*)((char*)base + byte) = v;
}

// ---------------- combined fp32->bf16 cast + rope table -------------------
__global__ __launch_bounds__(256) void cast_all_k(
    const float* __restrict__ hs, const float* __restrict__ wq,
    const float* __restrict__ wk, const float* __restrict__ wv,
    const float* __restrict__ wo, const int* __restrict__ pos,
    short* __restrict__ hs_bf, short* __restrict__ wqkv_bf, short* __restrict__ wo_bf,
    float* __restrict__ ct, float* __restrict__ st)
{
  int i = blockIdx.x * 256 + threadIdx.x;   // f4 index, total 4718592 + rope 131072
  if (i >= 4718592) {
    int id = i - 4718592;                    // SS*64 entries
    int s = id >> 6, fi = id & 63;
    double inv = pow(1.0e6, -(double)(2 * fi) / 128.0);
    double ang = (double)pos[s] * inv;
    ct[id] = (float)cos(ang);
    st[id] = (float)sin(ang);
    return;
  }
  const float* src; short* dst; int off;
  if (i < 2097152)       { src = hs; dst = hs_bf;            off = i; }
  else if (i < 3145728)  { src = wq; dst = wqkv_bf;          off = i - 2097152; }
  else if (i < 3407872)  { src = wk; dst = wqkv_bf + 4194304; off = i - 3145728; }
  else if (i < 3670016)  { src = wv; dst = wqkv_bf + 5242880; off = i - 3407872; }
  else                   { src = wo; dst = wo_bf;            off = i - 3670016; }
  const float4 v = ((const float4*)src)[off];
  short4 o;
  o.x = f2bf(v.x); o.y = f2bf(v.y); o.z = f2bf(v.z); o.w = f2bf(v.w);
  ((short4*)dst)[off] = o;
}

__device__ __forceinline__ float logsigf(float x)
{
  return (x >= 0.f) ? -log1pf(expf(-x)) : x - log1pf(expf(x));
}

// ---------------- fused QKV GEMM: minimal epilogue, bf16 raw stores -------
__global__ __launch_bounds__(256) void qkv_gemm_k(
    const short* __restrict__ A, const short* __restrict__ Bt,
    const float* __restrict__ bq, const float* __restrict__ bk,
    const float* __restrict__ bv,
    short* __restrict__ qraw, short* __restrict__ kraw, short* __restrict__ vb)
{
  const int K = HIDN, GX = 24;
  __shared__ short As[128 * 32];
  __shared__ short Bs[128 * 32];
  int orig = blockIdx.x;
  int wg = ((orig & 7) * 96) + (orig >> 3);  // nwg=768, bijective XCD swizzle
  int bm = (wg / GX) * 128, bn = (wg % GX) * 128;
  int tid = threadIdx.x;
  int wave = tid >> 6, lane = tid & 63;
  int wr = wave >> 1, wc = wave & 1;
  int l15 = lane & 15, g4i = lane >> 4;

  f32x4 acc[4][4];
  #pragma unroll
  for (int m = 0; m < 4; m++)
    #pragma unroll
    for (int n = 0; n < 4; n++) acc[m][n] = (f32x4){0.f, 0.f, 0.f, 0.f};

  int srow = lane >> 2;
  int scol = (lane & 3) * 8;
  const short* Abase = A + (size_t)bm * K;
  const short* Bbase = Bt + (size_t)bn * K;

  for (int k0 = 0; k0 < K; k0 += 32) {
    #pragma unroll
    for (int t = wave; t < 8; t += 4) {
      gld_lds16(Abase + (size_t)(t * 16 + srow) * K + k0 + scol, &As[t * 512]);
      gld_lds16(Bbase + (size_t)(t * 16 + srow) * K + k0 + scol, &Bs[t * 512]);
    }
    __syncthreads();
    int koff = g4i * 8;
    int ar = wr * 64 + l15;
    int br = wc * 64 + l15;
    bf16x8 af[4], bfr[4];
    #pragma unroll
    for (int m = 0; m < 4; m++) af[m] = *(const bf16x8*)&As[(ar + m * 16) * 32 + koff];
    #pragma unroll
    for (int n = 0; n < 4; n++) bfr[n] = *(const bf16x8*)&Bs[(br + n * 16) * 32 + koff];
    #pragma unroll
    for (int m = 0; m < 4; m++)
      #pragma unroll
      for (int n = 0; n < 4; n++)
        acc[m][n] = __builtin_amdgcn_mfma_f32_16x16x32_bf16(af[m], bfr[n], acc[m][n], 0, 0, 0);
    __syncthreads();
  }

  int proj = (bn < 2048) ? 0 : ((bn < 2560) ? 1 : 2);
  int nbase = (proj == 0) ? bn : ((proj == 1) ? bn - 2048 : bn - 2560);
  const float* bias = (proj == 0) ? bq : ((proj == 1) ? bk : bv);
  short* dst = (proj == 0) ? qraw : ((proj == 1) ? kraw : vb);
  int NHp = (proj == 0) ? HH : HKVV;

  int crow0 = wr * 64 + g4i * 4;
  int ccol0 = wc * 64 + l15;
  #pragma unroll
  for (int m = 0; m < 4; m++) {
    #pragma unroll
    for (int n = 0; n < 4; n++) {
      int nn = nbase + ccol0 + n * 16;
      float bvl = bias[nn];
      int hh = nn >> 7, d = nn & 127;
      #pragma unroll
      for (int r = 0; r < 4; r++) {
        int mm = bm + crow0 + m * 16 + r;
        int b = mm >> 11, s = mm & 2047;
        float val = acc[m][n][r] + bvl;
        dst[(size_t)((b * NHp + hh) * SS + s) * DD + d] = f2bf(val);
      }
    }
  }
}

// ---------------- bf16 MFMA GEMM (plain store), 1D grid XCD-swizzled ------
__global__ __launch_bounds__(256) void mfma_gemm_bt(
    const short* __restrict__ A, const short* __restrict__ Bt,
    float* __restrict__ C, int M, int N, int K, int gx, int q0)
{
  __shared__ short As[128 * 32];
  __shared__ short Bs[128 * 32];
  int orig = blockIdx.x;
  int wg = ((orig & 7) * q0) + (orig >> 3);
  int bm = (wg / gx) * 128, bn = (wg % gx) * 128;
  int tid = threadIdx.x;
  int wave = tid >> 6, lane = tid & 63;
  int wr = wave >> 1, wc = wave & 1;

  f32x4 acc[4][4];
  #pragma unroll
  for (int m = 0; m < 4; m++)
    #pragma unroll
    for (int n = 0; n < 4; n++) acc[m][n] = (f32x4){0.f, 0.f, 0.f, 0.f};

  int srow = lane >> 2;
  int scol = (lane & 3) * 8;
  const short* Abase = A + (size_t)bm * K;
  const short* Bbase = Bt + (size_t)bn * K;

  for (int k0 = 0; k0 < K; k0 += 32) {
    #pragma unroll
    for (int t = wave; t < 8; t += 4) {
      gld_lds16(Abase + (size_t)(t * 16 + srow) * K + k0 + scol, &As[t * 512]);
      gld_lds16(Bbase + (size_t)(t * 16 + srow) * K + k0 + scol, &Bs[t * 512]);
    }
    __syncthreads();
    int koff = (lane >> 4) * 8;
    int ar = wr * 64 + (lane & 15);
    int br = wc * 64 + (lane & 15);
    bf16x8 af[4], bfr[4];
    #pragma unroll
    for (int m = 0; m < 4; m++) af[m] = *(const bf16x8*)&As[(ar + m * 16) * 32 + koff];
    #pragma unroll
    for (int n = 0; n < 4; n++) bfr[n] = *(const bf16x8*)&Bs[(br + n * 16) * 32 + koff];
    #pragma unroll
    for (int m = 0; m < 4; m++)
      #pragma unroll
      for (int n = 0; n < 4; n++)
        acc[m][n] = __builtin_amdgcn_mfma_f32_16x16x32_bf16(af[m], bfr[n], acc[m][n], 0, 0, 0);
    __syncthreads();
  }

  int crow0 = wr * 64 + (lane >> 4) * 4;
  int ccol0 = wc * 64 + (lane & 15);
  #pragma unroll
  for (int m = 0; m < 4; m++)
    #pragma unroll
    for (int n = 0; n < 4; n++) {
      int nn = bn + ccol0 + n * 16;
      #pragma unroll
      for (int r = 0; r < 4; r++) {
        int mm = bm + crow0 + m * 16 + r;
        C[(size_t)mm * N + nn] = acc[m][n][r];
      }
    }
}

// ---------------- GLA pass A: gate+cumsum+k-softmax+Tc (from raw k) -------
__global__ __launch_bounds__(256) void gla_passA_k(
    const short* __restrict__ kraw, const short* __restrict__ vbb,
    float* __restrict__ Gc, float* __restrict__ Tc)
{
  int bx = blockIdx.x;             // bkvh*NCH + c
  int c = bx & 31;
  int bkvh = bx >> 5;
  __shared__ float Gs[64][128];
  __shared__ short KgT[128 * 64];
  __shared__ short VT[128 * 64];
  size_t rowbase = ((size_t)bkvh * SS + c * 64) * 128;
  int tid = threadIdx.x, w = tid >> 6, l = tid & 63, gi = l >> 4;
  int j = tid >> 2, d0 = (tid & 3) * 32;

  // load raw k, compute gate -> Gs
  float xk[32];
  {
    const bf16x8* k8 = (const bf16x8*)(kraw + rowbase + (size_t)j * 128 + d0);
    #pragma unroll
    for (int u = 0; u < 4; u++) {
      bf16x8 kv = k8[u];
      #pragma unroll
      for (int e = 0; e < 8; e++) {
        int idx = 8 * u + e;
        xk[idx] = bf2f(kv[e]);
        Gs[j][d0 + idx] = logsigf(xk[idx]) * (1.0f / 16.0f);
      }
    }
  }
  __syncthreads();
  if (tid < 128) {
    float run = 0.f;
    for (int jj = 0; jj < 64; jj++) { run += Gs[jj][tid]; Gs[jj][tid] = run; }
  }
  __syncthreads();
  {
    float4* gc4 = (float4*)(Gc + rowbase + (size_t)j * 128 + d0);
    const float4* gs4 = (const float4*)&Gs[j][d0];
    #pragma unroll
    for (int u = 0; u < 8; u++) gc4[u] = gs4[u];
  }
  // k softmax (row = 4 threads)
  float mx = xk[0];
  #pragma unroll
  for (int e = 1; e < 32; e++) mx = fmaxf(mx, xk[e]);
  mx = fmaxf(mx, __shfl_xor(mx, 1));
  mx = fmaxf(mx, __shfl_xor(mx, 2));
  float sum = 0.f;
  #pragma unroll
  for (int e = 0; e < 32; e++) { xk[e] = __expf(xk[e] - mx); sum += xk[e]; }
  sum += __shfl_xor(sum, 1);
  sum += __shfl_xor(sum, 2);
  float inv = 1.0f / sum;
  {
    const bf16x8* v8 = (const bf16x8*)(vbb + rowbase + (size_t)j * 128 + d0);
    #pragma unroll
    for (int u = 0; u < 4; u++) {
      bf16x8 vv = v8[u];
      #pragma unroll
      for (int e = 0; e < 8; e++) {
        int d = d0 + u * 8 + e;
        float kg = xk[u * 8 + e] * inv * __expf(Gs[63][d] - Gs[j][d]);
        lds_w16_swz(KgT, d, 64, j, f2bf(kg));
        lds_w16_swz(VT, d, 64, j, vv[e]);
      }
    }
  }
  __syncthreads();
  // Tc[vv][kk] = sum_j V[j][vv] * Kg[j][kk]; wave w owns vv in [32w,32w+32)
  f32x4 acc[2][8];
  #pragma unroll
  for (int m = 0; m < 2; m++)
    #pragma unroll
    for (int n = 0; n < 8; n++) acc[m][n] = (f32x4){0.f, 0.f, 0.f, 0.f};
  #pragma unroll
  for (int k0i = 0; k0i < 2; k0i++) {
    int k0 = k0i * 32 + gi * 8;
    bf16x8 af[2];
    #pragma unroll
    for (int m = 0; m < 2; m++) af[m] = ldsA(VT, 32 * w + 16 * m + (l & 15), 64, k0);
    #pragma unroll
    for (int n = 0; n < 8; n++) {
      bf16x8 bfr = ldsA(KgT, 16 * n + (l & 15), 64, k0);
      #pragma unroll
      for (int m = 0; m < 2; m++)
        acc[m][n] = __builtin_amdgcn_mfma_f32_16x16x32_bf16(af[m], bfr, acc[m][n], 0, 0, 0);
    }
  }
  size_t tbase = (size_t)bx * 16384;
  #pragma unroll
  for (int m = 0; m < 2; m++)
    #pragma unroll
    for (int n = 0; n < 8; n++)
      #pragma unroll
      for (int r = 0; r < 4; r++) {
        int vv = 32 * w + 16 * m + 4 * gi + r;
        int kk = 16 * n + (l & 15);
        Tc[tbase + (size_t)vv * 128 + kk] = acc[m][n][r];
      }
}

// ---------------- GLA pass B: scan; Tc is [v][k]; writes hT[v][k] bf16 ----
__global__ __launch_bounds__(256) void gla_passB_k(
    const float* __restrict__ Tc, const float* __restrict__ Gc,
    short* __restrict__ hT)
{
  int id = blockIdx.x * 256 + threadIdx.x; // (bkvh, v, k)
  int bkvh = id >> 14;
  int vk = id & 16383;
  int kk = vk & 127;
  float h = 0.f;
  for (int c = 0; c < NCH; ++c) {
    size_t cb = ((size_t)(bkvh * NCH + c) << 14);
    hT[cb + vk] = f2bf(h);
    float gl = Gc[((size_t)bkvh * SS + c * 64 + 63) * 128 + kk];
    h = h * __expf(gl) + Tc[cb + vk];
  }
}

// ---------------- GLA pass C: inline q/k softmax + MFMA -------------------
__global__ __launch_bounds__(256) void gla_passC_k(
    const short* __restrict__ qraw, const short* __restrict__ kraw,
    const short* __restrict__ vbb, const float* __restrict__ Gc,
    const short* __restrict__ hT, short* __restrict__ olin)
{
  int bx = blockIdx.x;            // (b*H+h)*NCH + c
  int c = bx & 31;
  int bh = bx >> 5;
  int b = bh >> 4, hq = bh & 15;
  int bkvh = b * HKVV + (hq >> 2);
  __shared__ short QeB[64 * 128];
  __shared__ short KeB[64 * 128];  // first 4096 reused as AmB after B1
  __shared__ short VtB[128 * 64];
  int tid = threadIdx.x, w = tid >> 6, l = tid & 63, g = l >> 4;
  size_t qrow = ((size_t)bh * SS + c * 64) * 128;
  size_t krow = ((size_t)bkvh * SS + c * 64) * 128;

  const short* hTb = hT + (((size_t)(bkvh * NCH + c)) << 14);
  bf16x8 hB[4][2];
  #pragma unroll
  for (int k0i = 0; k0i < 4; k0i++)
    #pragma unroll
    for (int nt = 0; nt < 2; nt++)
      hB[k0i][nt] = *(const bf16x8*)(hTb + (size_t)(32 * w + 16 * nt + (l & 15)) * 128 + k0i * 32 + g * 8);

  // async stage raw q,k into QeB/KeB (pre-swizzled source); V via regs
  {
    const short* qg = qraw + qrow;
    const short* kg = kraw + krow;
    for (int c0 = w * 64; c0 < 1024; c0 += 256) {
      int cc = c0 + l, row = cc >> 4;
      int gb = (cc << 4) ^ ((row & 7) << 4);
      gld_lds16((const short*)((const char*)qg + gb), QeB + c0 * 8);
      gld_lds16((const short*)((const char*)kg + gb), KeB + c0 * 8);
    }
    int j = tid >> 2, d0 = (tid & 3) * 32;
    const bf16x8* v8 = (const bf16x8*)(vbb + krow + (size_t)j * 128 + d0);
    #pragma unroll
    for (int u = 0; u < 4; u++) {
      bf16x8 vv = v8[u];
      #pragma unroll
      for (int e = 0; e < 8; e++)
        lds_w16_swz(VtB, d0 + u * 8 + e, 64, j, vv[e]);
    }
  }
  __syncthreads(); // B0a: staging complete

  // in-place softmax + gate scaling (each thread owns its cells)
  {
    int j = tid >> 2, d0 = (tid & 3) * 32;
    float gcv[32];
    const float* gp = Gc + krow + (size_t)j * 128 + d0;
    #pragma unroll
    for (int u = 0; u < 8; u++) {
      float4 t = ((const float4*)gp)[u];
      gcv[4 * u] = t.x; gcv[4 * u + 1] = t.y; gcv[4 * u + 2] = t.z; gcv[4 * u + 3] = t.w;
    }
    float x[32];
    // q: softmax * exp(gc)
    #pragma unroll
    for (int u = 0; u < 4; u++) {
      bf16x8 x8 = ldsA(QeB, j, 128, d0 + 8 * u);
      #pragma unroll
      for (int e = 0; e < 8; e++) x[8 * u + e] = bf2f(x8[e]);
    }
    float mx = x[0];
    #pragma unroll
    for (int e = 1; e < 32; e++) mx = fmaxf(mx, x[e]);
    mx = fmaxf(mx, __shfl_xor(mx, 1));
    mx = fmaxf(mx, __shfl_xor(mx, 2));
    float sum = 0.f;
    #pragma unroll
    for (int e = 0; e < 32; e++) { x[e] = __expf(x[e] - mx); sum += x[e]; }
    sum += __shfl_xor(sum, 1);
    sum += __shfl_xor(sum, 2);
    float inv = 1.0f / sum;
    #pragma unroll
    for (int e = 0; e < 32; e++)
      lds_w16_swz(QeB, j, 128, d0 + e, f2bf(x[e] * inv * __expf(gcv[e])));
    // k: softmax * exp(-gc)
    #pragma unroll
    for (int u = 0; u < 4; u++) {
      bf16x8 x8 = ldsA(KeB, j, 128, d0 + 8 * u);
      #pragma unroll
      for (int e = 0; e < 8; e++) x[8 * u + e] = bf2f(x8[e]);
    }
    mx = x[0];
    #pragma unroll
    for (int e = 1; e < 32; e++) mx = fmaxf(mx, x[e]);
    mx = fmaxf(mx, __shfl_xor(mx, 1));
    mx = fmaxf(mx, __shfl_xor(mx, 2));
    sum = 0.f;
    #pragma unroll
    for (int e = 0; e < 32; e++) { x[e] = __expf(x[e] - mx); sum += x[e]; }
    sum += __shfl_xor(sum, 1);
    sum += __shfl_xor(sum, 2);
    inv = 1.0f / sum;
    #pragma unroll
    for (int e = 0; e < 32; e++)
      lds_w16_swz(KeB, j, 128, d0 + e, f2bf(x[e] * inv * __expf(-gcv[e])));
  }
  __syncthreads(); // B0b

  f32x4 acc1[4];
  #pragma unroll
  for (int m = 0; m < 4; m++) acc1[m] = (f32x4){0.f, 0.f, 0.f, 0.f};
  #pragma unroll
  for (int k0i = 0; k0i < 4; k0i++) {
    int k0 = k0i * 32 + g * 8;
    bf16x8 bk = ldsA(KeB, 16 * w + (l & 15), 128, k0);
    #pragma unroll
    for (int m = 0; m < 4; m++) {
      bf16x8 af = ldsA(QeB, 16 * m + (l & 15), 128, k0);
      acc1[m] = __builtin_amdgcn_mfma_f32_16x16x32_bf16(af, bk, acc1[m], 0, 0, 0);
    }
  }
  __syncthreads(); // B1
  short* AmB = KeB;
  #pragma unroll
  for (int m = 0; m < 4; m++)
    #pragma unroll
    for (int r = 0; r < 4; r++) {
      int i = 16 * m + 4 * g + r;
      int j = 16 * w + (l & 15);
      float val = (j <= i) ? acc1[m][r] : 0.f;
      lds_w16_swz(AmB, i, 64, j, f2bf(val));
    }
  __syncthreads(); // B2

  f32x4 acc[4][2];
  #pragma unroll
  for (int m = 0; m < 4; m++)
    #pragma unroll
    for (int nt = 0; nt < 2; nt++) acc[m][nt] = (f32x4){0.f, 0.f, 0.f, 0.f};
  #pragma unroll
  for (int k0i = 0; k0i < 2; k0i++) {
    int k0 = k0i * 32 + g * 8;
    bf16x8 bfr[2];
    #pragma unroll
    for (int nt = 0; nt < 2; nt++) bfr[nt] = ldsA(VtB, 32 * w + 16 * nt + (l & 15), 64, k0);
    #pragma unroll
    for (int m = 0; m < 4; m++) {
      bf16x8 af = ldsA(AmB, 16 * m + (l & 15), 64, k0);
      #pragma unroll
      for (int nt = 0; nt < 2; nt++)
        acc[m][nt] = __builtin_amdgcn_mfma_f32_16x16x32_bf16(af, bfr[nt], acc[m][nt], 0, 0, 0);
    }
  }
  #pragma unroll
  for (int k0i = 0; k0i < 4; k0i++) {
    int k0 = k0i * 32 + g * 8;
    #pragma unroll
    for (int m = 0; m < 4; m++) {
      bf16x8 af = ldsA(QeB, 16 * m + (l & 15), 128, k0);
      #pragma unroll
      for (int nt = 0; nt < 2; nt++)
        acc[m][nt] = __builtin_amdgcn_mfma_f32_16x16x32_bf16(af, hB[k0i][nt], acc[m][nt], 0, 0, 0);
    }
  }
  #pragma unroll
  for (int m = 0; m < 4; m++)
    #pragma unroll
    for (int nt = 0; nt < 2; nt++)
      #pragma unroll
      for (int r = 0; r < 4; r++) {
        int i = 16 * m + 4 * g + r, d = 32 * w + 16 * nt + (l & 15);
        olin[qrow + (size_t)i * 128 + d] = f2bf(acc[m][nt][r]);
      }
}

// ---------------- windowed attention: inline rope + MFMA + mix ------------
__global__ __launch_bounds__(256) void win_attn_k(
    const short* __restrict__ qraw, const short* __restrict__ kraw,
    const short* __restrict__ vb, const short* __restrict__ olin,
    const float* __restrict__ ct, const float* __restrict__ st,
    short* __restrict__ obf)
{
  int bx = blockIdx.x;            // (b*H+h)*NBLK + n
  int n = bx & 31;
  int bh = bx >> 5;
  int b = bh >> 4, hq = bh & 15;
  int bkvh = b * HKVV + (hq >> 2);
  __shared__ short Qs[64 * 128];   // then P (bf16)
  __shared__ short Ks[128 * 128];  // then V^T (bf16)
  __shared__ float wred[2][4][64];
  int tid = threadIdx.x, w = tid >> 6, l = tid & 63, g = l >> 4;

  // stage roped Q and K window from raw (partner col = d ^ 64 via shfl_xor(.,2))
  {
    int j = tid >> 2, c0g = (tid & 3) * 32;
    float sgn = (c0g < 64) ? -1.f : 1.f;
    int fb = c0g & 63;
    // Q row n*64+j
    {
      int sq = n * 64 + j;
      const short* qr = qraw + ((size_t)bh * SS + sq) * 128 + c0g;
      const float* ctp = ct + (size_t)sq * 64 + fb;
      const float* stp = st + (size_t)sq * 64 + fb;
      #pragma unroll
      for (int u = 0; u < 4; u++) {
        bf16x8 x8 = *(const bf16x8*)(qr + 8 * u);
        float4 c4a = *(const float4*)(ctp + 8 * u);
        float4 c4b = *(const float4*)(ctp + 8 * u + 4);
        float4 s4a = *(const float4*)(stp + 8 * u);
        float4 s4b = *(const float4*)(stp + 8 * u + 4);
        float cc[8] = {c4a.x, c4a.y, c4a.z, c4a.w, c4b.x, c4b.y, c4b.z, c4b.w};
        float sv[8] = {s4a.x, s4a.y, s4a.z, s4a.w, s4b.x, s4b.y, s4b.z, s4b.w};
        #pragma unroll
        for (int e = 0; e < 8; e++) {
          float xv = bf2f(x8[e]);
          float pv = __shfl_xor(xv, 2);
          lds_w16_swz(Qs, j, 128, c0g + 8 * u + e, f2bf(xv * cc[e] + sgn * pv * sv[e]));
        }
      }
    }
    // K rows (n-1)*64 + ch*64 + j  (kp<0 is block-uniform: only n==0, ch==0)
    #pragma unroll
    for (int ch = 0; ch < 2; ch++) {
      int kp = (n - 1) * 64 + ch * 64 + j;
      if (kp >= 0) {
        const short* kr = kraw + ((size_t)bkvh * SS + kp) * 128 + c0g;
        const float* ctp = ct + (size_t)kp * 64 + fb;
        const float* stp = st + (size_t)kp * 64 + fb;
        #pragma unroll
        for (int u = 0; u < 4; u++) {
          bf16x8 x8 = *(const bf16x8*)(kr + 8 * u);
          float4 c4a = *(const float4*)(ctp + 8 * u);
          float4 c4b = *(const float4*)(ctp + 8 * u + 4);
          float4 s4a = *(const float4*)(stp + 8 * u);
          float4 s4b = *(const float4*)(stp + 8 * u + 4);
          float cc[8] = {c4a.x, c4a.y, c4a.z, c4a.w, c4b.x, c4b.y, c4b.z, c4b.w};
          float sv[8] = {s4a.x, s4a.y, s4a.z, s4a.w, s4b.x, s4b.y, s4b.z, s4b.w};
          #pragma unroll
          for (int e = 0; e < 8; e++) {
            float xv = bf2f(x8[e]);
            float pv = __shfl_xor(xv, 2);
            lds_w16_swz(Ks, ch * 64 + j, 128, c0g + 8 * u + e,
                        f2bf(xv * cc[e] + sgn * pv * sv[e]));
          }
        }
      } else {
        #pragma unroll
        for (int e = 0; e < 32; e++)
          lds_w16_swz(Ks, ch * 64 + j, 128, c0g + e, 0);
      }
    }
  }
  __syncthreads(); // B0

  f32x4 acc[4][2];
  #pragma unroll
  for (int m = 0; m < 4; m++)
    #pragma unroll
    for (int nt = 0; nt < 2; nt++) acc[m][nt] = (f32x4){0.f, 0.f, 0.f, 0.f};
  #pragma unroll
  for (int k0i = 0; k0i < 4; k0i++) {
    int k0 = k0i * 32 + g * 8;
    bf16x8 bfr[2];
    #pragma unroll
    for (int nt = 0; nt < 2; nt++) bfr[nt] = ldsA(Ks, 32 * w + 16 * nt + (l & 15), 128, k0);
    #pragma unroll
    for (int m = 0; m < 4; m++) {
      bf16x8 af = ldsA(Qs, 16 * m + (l & 15), 128, k0);
      #pragma unroll
      for (int nt = 0; nt < 2; nt++)
        acc[m][nt] = __builtin_amdgcn_mfma_f32_16x16x32_bf16(af, bfr[nt], acc[m][nt], 0, 0, 0);
    }
  }

  const float scale = 0.08838834764831845f;
  float mx[4][4];
  #pragma unroll
  for (int m = 0; m < 4; m++)
    #pragma unroll
    for (int r = 0; r < 4; r++) mx[m][r] = -1e30f;
  #pragma unroll
  for (int m = 0; m < 4; m++)
    #pragma unroll
    for (int nt = 0; nt < 2; nt++)
      #pragma unroll
      for (int r = 0; r < 4; r++) {
        int i = 16 * m + 4 * g + r;
        int j = 32 * w + 16 * nt + (l & 15);
        int kp = (n - 1) * 64 + j;
        bool valid = (j >= i) && (j <= i + 64) && (kp >= 0);
        float sc = valid ? acc[m][nt][r] * scale : -1e30f;
        acc[m][nt][r] = sc;
        mx[m][r] = fmaxf(mx[m][r], sc);
      }
  #pragma unroll
  for (int m = 0; m < 4; m++)
    #pragma unroll
    for (int r = 0; r < 4; r++) {
      #pragma unroll
      for (int msk = 1; msk < 16; msk <<= 1) mx[m][r] = fmaxf(mx[m][r], __shfl_xor(mx[m][r], msk));
    }
  if ((l & 15) == 0)
    #pragma unroll
    for (int m = 0; m < 4; m++)
      #pragma unroll
      for (int r = 0; r < 4; r++) wred[0][w][16 * m + 4 * g + r] = mx[m][r];
  __syncthreads(); // B1

  float mrow[4][4], sm[4][4];
  #pragma unroll
  for (int m = 0; m < 4; m++)
    #pragma unroll
    for (int r = 0; r < 4; r++) {
      int i = 16 * m + 4 * g + r;
      mrow[m][r] = fmaxf(fmaxf(wred[0][0][i], wred[0][1][i]), fmaxf(wred[0][2][i], wred[0][3][i]));
      sm[m][r] = 0.f;
    }
  #pragma unroll
  for (int m = 0; m < 4; m++)
    #pragma unroll
    for (int nt = 0; nt < 2; nt++)
      #pragma unroll
      for (int r = 0; r < 4; r++) {
        float p = __expf(acc[m][nt][r] - mrow[m][r]);
        acc[m][nt][r] = p;
        sm[m][r] += p;
      }
  #pragma unroll
  for (int m = 0; m < 4; m++)
    #pragma unroll
    for (int r = 0; r < 4; r++) {
      #pragma unroll
      for (int msk = 1; msk < 16; msk <<= 1) sm[m][r] += __shfl_xor(sm[m][r], msk);
    }
  if ((l & 15) == 0)
    #pragma unroll
    for (int m = 0; m < 4; m++)
      #pragma unroll
      for (int r = 0; r < 4; r++) wred[1][w][16 * m + 4 * g + r] = sm[m][r];
  __syncthreads(); // B2

  #pragma unroll
  for (int m = 0; m < 4; m++)
    #pragma unroll
    for (int r = 0; r < 4; r++) {
      int i = 16 * m + 4 * g + r;
      float s = wred[1][0][i] + wred[1][1][i] + wred[1][2][i] + wred[1][3][i];
      float inv = 1.0f / s;
      #pragma unroll
      for (int nt = 0; nt < 2; nt++) {
        int j = 32 * w + 16 * nt + (l & 15);
        lds_w16_swz(Qs, i, 128, j, f2bf(acc[m][nt][r] * inv));
      }
    }
  {
    int j = tid >> 1, dh = (tid & 1) * 64;
    int kp = (n - 1) * 64 + j;
    const short* vrow = vb + ((size_t)bkvh * SS + kp) * 128 + dh;
    #pragma unroll
    for (int u = 0; u < 8; u++) {
      bf16x8 vv;
      if (kp >= 0) vv = *(const bf16x8*)(vrow + u * 8);
      else vv = (bf16x8){0, 0, 0, 0, 0, 0, 0, 0};
      #pragma unroll
      for (int i2 = 0; i2 < 8; i2++)
        lds_w16_swz(Ks, dh + u * 8 + i2, 128, j, vv[i2]);
    }
  }
  __syncthreads(); // B3

  f32x4 o[4][2];
  #pragma unroll
  for (int m = 0; m < 4; m++)
    #pragma unroll
    for (int nt = 0; nt < 2; nt++) o[m][nt] = (f32x4){0.f, 0.f, 0.f, 0.f};
  #pragma unroll
  for (int k0i = 0; k0i < 4; k0i++) {
    int k0 = k0i * 32 + g * 8;
    bf16x8 bfr[2];
    #pragma unroll
    for (int nt = 0; nt < 2; nt++) bfr[nt] = ldsA(Ks, 32 * w + 16 * nt + (l & 15), 128, k0);
    #pragma unroll
    for (int m = 0; m < 4; m++) {
      bf16x8 af = ldsA(Qs, 16 * m + (l & 15), 128, k0);
      #pragma unroll
      for (int nt = 0; nt < 2; nt++)
        o[m][nt] = __builtin_amdgcn_mfma_f32_16x16x32_bf16(af, bfr[nt], o[m][nt], 0, 0, 0);
    }
  }
  #pragma unroll
  for (int m = 0; m < 4; m++)
    #pragma unroll
    for (int nt = 0; nt < 2; nt++)
      #pragma unroll
      for (int r = 0; r < 4; r++) {
        int i = 16 * m + 4 * g + r, d = 32 * w + 16 * nt + (l & 15);
        float ol = bf2f(olin[((size_t)bh * SS + n * 64 + i) * 128 + d]);
        float val = 0.5f * o[m][nt][r] + 0.5f * ol;
        obf[((size_t)(b * SS + n * 64 + i)) * HIDN + hq * 128 + d] = f2bf(val);
      }
}

// --------------------------------------------------------------------------
extern "C" void kernel_launch(void* const* d_in, const int* in_sizes, int n_in,
                              void* d_out, int out_size, void* d_ws, size_t ws_size,
                              hipStream_t stream)
{
  const float* hs = (const float*)d_in[0];
  const int*  pos = (const int*)d_in[1];
  const float* Wq = (const float*)d_in[2];
  const float* bq = (const float*)d_in[3];
  const float* Wk = (const float*)d_in[4];
  const float* bk = (const float*)d_in[5];
  const float* Wv = (const float*)d_in[6];
  const float* bv = (const float*)d_in[7];
  const float* Wo = (const float*)d_in[8];
  float* out = (float*)d_out;

  float* w = (float*)d_ws;
  const size_t QSZ = (size_t)BB * HH * SS * DD;         // 8388608
  const size_t KSZ = (size_t)BB * HKVV * SS * DD;       // 2097152
  const size_t TSZ = (size_t)BB * HKVV * NCH * DD * DD; // 4194304
  short* hs_bf = (short*)w; w += QSZ / 2;
  short* qraw  = (short*)w; w += QSZ / 2;
  short* kraw  = (short*)w; w += KSZ / 2;
  short* vb    = (short*)w; w += KSZ / 2;
  float* Gc    = w; w += KSZ;
  float* Tc    = w; w += TSZ;             // hosts obf after passB
  short* hT    = (short*)w; w += TSZ / 2;
  short* olin  = (short*)w; w += QSZ / 2;
  float* ct    = w; w += (size_t)SS * 64;
  float* st    = w; w += (size_t)SS * 64;
  short* wo_bf = (short*)w; w += (size_t)HIDN * HIDN / 2;
  short* wqkv_bf = (short*)w; w += (size_t)3072 * HIDN / 2;

  short* obf = (short*)Tc;

  dim3 blk(256);
  const int M = BB * SS; // 4096

  cast_all_k<<<dim3(18944), blk, 0, stream>>>(hs, Wq, Wk, Wv, Wo, pos,
                                              hs_bf, wqkv_bf, wo_bf, ct, st);

  qkv_gemm_k<<<dim3(768), blk, 0, stream>>>(hs_bf, wqkv_bf, bq, bk, bv,
                                            qraw, kraw, vb);

  gla_passA_k<<<dim3(BB * HKVV * NCH), blk, 0, stream>>>(kraw, vb, Gc, Tc);
  gla_passB_k<<<dim3(BB * HKVV * DD * DD / 256), blk, 0, stream>>>(Tc, Gc, hT);
  gla_passC_k<<<dim3(BB * HH * NCH), blk, 0, stream>>>(qraw, kraw, vb, Gc, hT, olin);

  win_attn_k<<<dim3(BB * HH * NBLK), blk, 0, stream>>>(qraw, kraw, vb, olin, ct, st, obf);

  mfma_gemm_bt<<<dim3(512), blk, 0, stream>>>(obf, wo_bf, out, M, HIDN, HIDN, 16, 64);
}

// Round 11
// 229.322 us; speedup vs baseline: 1.1514x; 1.1514x over previous
//
#include <hip/hip_runtime.h>
#include <hip/hip_bf16.h>
#include <math.h>

#define BB   2
#define SS   2048
#define HIDN 2048
#define HH   16
#define HKVV 4
#define DD   128
#define NCH  32   // S/CHUNK
#define CHK  64
#define NBLK 32   // S/WIN

typedef __attribute__((ext_vector_type(8))) short bf16x8;
typedef __attribute__((ext_vector_type(4))) float f32x4;

__device__ __forceinline__ short f2bf(float x)
{
  __hip_bfloat16 h = __float2bfloat16(x);
  return *(short*)&h;
}
__device__ __forceinline__ float bf2f(short x)
{
  return __uint_as_float(((uint)(ushort)x) << 16);
}

__device__ __forceinline__ void gld_lds16(const short* g, short* lds)
{
  __builtin_amdgcn_global_load_lds(
      (const __attribute__((address_space(1))) void*)g,
      (__attribute__((address_space(3))) void*)lds, 16, 0, 0);
}

// swizzled LDS helpers: byte ^= ((row&7)<<4) within each 8-row stripe
__device__ __forceinline__ bf16x8 ldsA(const short* base, int row, int rs, int ks)
{
  int byte = (row * rs + ks) * 2;
  byte ^= ((row & 7) << 4);
  __builtin_assume((byte & 15) == 0);
  return *(const bf16x8*)((const char*)base + byte);
}
__device__ __forceinline__ void lds_w16_swz(short* base, int row, int rs, int ks, short v)
{
  int byte = (row * rs + ks) * 2;
  byte ^= ((row & 7) << 4);
  *(short*)((char*)base + byte) = v;
}

// ---------------- combined fp32->bf16 cast + rope table -------------------
__global__ __launch_bounds__(256) void cast_all_k(
    const float* __restrict__ hs, const float* __restrict__ wq,
    const float* __restrict__ wk, const float* __restrict__ wv,
    const float* __restrict__ wo, const int* __restrict__ pos,
    short* __restrict__ hs_bf, short* __restrict__ wqkv_bf, short* __restrict__ wo_bf,
    float* __restrict__ ct, float* __restrict__ st)
{
  int i = blockIdx.x * 256 + threadIdx.x;   // f4 index, total 4718592 + rope 131072
  if (i >= 4718592) {
    int id = i - 4718592;                    // SS*64 entries
    int s = id >> 6, fi = id & 63;
    double inv = pow(1.0e6, -(double)(2 * fi) / 128.0);
    double ang = (double)pos[s] * inv;
    ct[id] = (float)cos(ang);
    st[id] = (float)sin(ang);
    return;
  }
  const float* src; short* dst; int off;
  if (i < 2097152)       { src = hs; dst = hs_bf;            off = i; }
  else if (i < 3145728)  { src = wq; dst = wqkv_bf;          off = i - 2097152; }
  else if (i < 3407872)  { src = wk; dst = wqkv_bf + 4194304; off = i - 3145728; }
  else if (i < 3670016)  { src = wv; dst = wqkv_bf + 5242880; off = i - 3407872; }
  else                   { src = wo; dst = wo_bf;            off = i - 3670016; }
  const float4 v = ((const float4*)src)[off];
  short4 o;
  o.x = f2bf(v.x); o.y = f2bf(v.y); o.z = f2bf(v.z); o.w = f2bf(v.w);
  ((short4*)dst)[off] = o;
}

__device__ __forceinline__ float logsigf(float x)
{
  return (x >= 0.f) ? -log1pf(expf(-x)) : x - log1pf(expf(x));
}

// ---------------- fused QKV GEMM: minimal epilogue (r4/r9-proven) ---------
// q/k: f32 head-layout stores; v: bf16 store. No barriers/LDS in epilogue.
__global__ __launch_bounds__(256) void qkv_gemm_k(
    const short* __restrict__ A, const short* __restrict__ Bt,
    const float* __restrict__ bq, const float* __restrict__ bk,
    const float* __restrict__ bv,
    float* __restrict__ qbuf, float* __restrict__ kbuf, short* __restrict__ vb)
{
  const int K = HIDN, GX = 24;
  __shared__ short As[128 * 32];
  __shared__ short Bs[128 * 32];
  int orig = blockIdx.x;
  int wg = ((orig & 7) * 96) + (orig >> 3);  // nwg=768, bijective XCD swizzle
  int bm = (wg / GX) * 128, bn = (wg % GX) * 128;
  int tid = threadIdx.x;
  int wave = tid >> 6, lane = tid & 63;
  int wr = wave >> 1, wc = wave & 1;
  int l15 = lane & 15, g4i = lane >> 4;

  f32x4 acc[4][4];
  #pragma unroll
  for (int m = 0; m < 4; m++)
    #pragma unroll
    for (int n = 0; n < 4; n++) acc[m][n] = (f32x4){0.f, 0.f, 0.f, 0.f};

  int srow = lane >> 2;
  int scol = (lane & 3) * 8;
  const short* Abase = A + (size_t)bm * K;
  const short* Bbase = Bt + (size_t)bn * K;

  for (int k0 = 0; k0 < K; k0 += 32) {
    #pragma unroll
    for (int t = wave; t < 8; t += 4) {
      gld_lds16(Abase + (size_t)(t * 16 + srow) * K + k0 + scol, &As[t * 512]);
      gld_lds16(Bbase + (size_t)(t * 16 + srow) * K + k0 + scol, &Bs[t * 512]);
    }
    __syncthreads();
    int koff = g4i * 8;
    int ar = wr * 64 + l15;
    int br = wc * 64 + l15;
    bf16x8 af[4], bfr[4];
    #pragma unroll
    for (int m = 0; m < 4; m++) af[m] = *(const bf16x8*)&As[(ar + m * 16) * 32 + koff];
    #pragma unroll
    for (int n = 0; n < 4; n++) bfr[n] = *(const bf16x8*)&Bs[(br + n * 16) * 32 + koff];
    #pragma unroll
    for (int m = 0; m < 4; m++)
      #pragma unroll
      for (int n = 0; n < 4; n++)
        acc[m][n] = __builtin_amdgcn_mfma_f32_16x16x32_bf16(af[m], bfr[n], acc[m][n], 0, 0, 0);
    __syncthreads();
  }

  int proj = (bn < 2048) ? 0 : ((bn < 2560) ? 1 : 2);
  int nbase = (proj == 0) ? bn : ((proj == 1) ? bn - 2048 : bn - 2560);
  const float* bias = (proj == 0) ? bq : ((proj == 1) ? bk : bv);
  float* fdst = (proj == 0) ? qbuf : kbuf;
  int NHp = (proj == 0) ? HH : HKVV;

  int crow0 = wr * 64 + g4i * 4;
  int ccol0 = wc * 64 + l15;
  #pragma unroll
  for (int m = 0; m < 4; m++) {
    #pragma unroll
    for (int n = 0; n < 4; n++) {
      int nn = nbase + ccol0 + n * 16;
      float bvl = bias[nn];
      int hh = nn >> 7, d = nn & 127;
      #pragma unroll
      for (int r = 0; r < 4; r++) {
        int mm = bm + crow0 + m * 16 + r;
        int b = mm >> 11, s = mm & 2047;
        float val = acc[m][n][r] + bvl;
        size_t idx = (size_t)((b * NHp + hh) * SS + s) * DD + d;
        if (proj == 2) vb[idx] = f2bf(val);
        else fdst[idx] = val;
      }
    }
  }
}

// ---------------- prep: softmax + rope (+gate for k) from f32 q/k ---------
__global__ __launch_bounds__(256) void prep_k(
    const float* __restrict__ qbuf, const float* __restrict__ kbuf,
    const float* __restrict__ ct, const float* __restrict__ st,
    short* __restrict__ qsm, short* __restrict__ sqb,
    short* __restrict__ ksm, short* __restrict__ skb, float* __restrict__ gbuf)
{
  int rowid = blockIdx.x * 8 + (threadIdx.x >> 5);
  int l32 = threadIdx.x & 31;
  bool isq = rowid < (BB * HH * SS);
  int row = isq ? rowid : rowid - BB * HH * SS;
  int s = row & (SS - 1);
  size_t base = (size_t)row * 128;
  int c = l32 * 4;
  const float* src = isq ? qbuf : kbuf;
  float4 x4 = *(const float4*)(src + base + c);
  float x0 = x4.x, x1 = x4.y, x2 = x4.z, x3 = x4.w;

  // rope
  float p0 = __shfl_xor(x0, 16), p1 = __shfl_xor(x1, 16);
  float p2 = __shfl_xor(x2, 16), p3 = __shfl_xor(x3, 16);
  int f = c & 63;
  float4 cv = *(const float4*)(ct + (size_t)s * 64 + f);
  float4 sv = *(const float4*)(st + (size_t)s * 64 + f);
  float sgn = (c < 64) ? -1.f : 1.f;
  short4 r4;
  r4.x = f2bf(x0 * cv.x + sgn * p0 * sv.x);
  r4.y = f2bf(x1 * cv.y + sgn * p1 * sv.y);
  r4.z = f2bf(x2 * cv.z + sgn * p2 * sv.z);
  r4.w = f2bf(x3 * cv.w + sgn * p3 * sv.w);
  *(short4*)((isq ? sqb : skb) + base + c) = r4;

  // gate (k only)
  if (!isq) {
    float4 gv = make_float4(logsigf(x0) * (1.0f / 16.0f), logsigf(x1) * (1.0f / 16.0f),
                            logsigf(x2) * (1.0f / 16.0f), logsigf(x3) * (1.0f / 16.0f));
    *(float4*)(gbuf + base + c) = gv;
  }

  // softmax
  float m = fmaxf(fmaxf(x0, x1), fmaxf(x2, x3));
  #pragma unroll
  for (int msk = 1; msk < 32; msk <<= 1) m = fmaxf(m, __shfl_xor(m, msk));
  float e0 = __expf(x0 - m), e1 = __expf(x1 - m), e2 = __expf(x2 - m), e3 = __expf(x3 - m);
  float sum = e0 + e1 + e2 + e3;
  #pragma unroll
  for (int msk = 1; msk < 32; msk <<= 1) sum += __shfl_xor(sum, msk);
  float inv = 1.0f / sum;
  short4 o;
  o.x = f2bf(e0 * inv); o.y = f2bf(e1 * inv); o.z = f2bf(e2 * inv); o.w = f2bf(e3 * inv);
  *(short4*)((isq ? qsm : ksm) + base + c) = o;
}

// ---------------- bf16 MFMA GEMM (plain store), 1D grid XCD-swizzled ------
__global__ __launch_bounds__(256) void mfma_gemm_bt(
    const short* __restrict__ A, const short* __restrict__ Bt,
    float* __restrict__ C, int M, int N, int K, int gx, int q0)
{
  __shared__ short As[128 * 32];
  __shared__ short Bs[128 * 32];
  int orig = blockIdx.x;
  int wg = ((orig & 7) * q0) + (orig >> 3);
  int bm = (wg / gx) * 128, bn = (wg % gx) * 128;
  int tid = threadIdx.x;
  int wave = tid >> 6, lane = tid & 63;
  int wr = wave >> 1, wc = wave & 1;

  f32x4 acc[4][4];
  #pragma unroll
  for (int m = 0; m < 4; m++)
    #pragma unroll
    for (int n = 0; n < 4; n++) acc[m][n] = (f32x4){0.f, 0.f, 0.f, 0.f};

  int srow = lane >> 2;
  int scol = (lane & 3) * 8;
  const short* Abase = A + (size_t)bm * K;
  const short* Bbase = Bt + (size_t)bn * K;

  for (int k0 = 0; k0 < K; k0 += 32) {
    #pragma unroll
    for (int t = wave; t < 8; t += 4) {
      gld_lds16(Abase + (size_t)(t * 16 + srow) * K + k0 + scol, &As[t * 512]);
      gld_lds16(Bbase + (size_t)(t * 16 + srow) * K + k0 + scol, &Bs[t * 512]);
    }
    __syncthreads();
    int koff = (lane >> 4) * 8;
    int ar = wr * 64 + (lane & 15);
    int br = wc * 64 + (lane & 15);
    bf16x8 af[4], bfr[4];
    #pragma unroll
    for (int m = 0; m < 4; m++) af[m] = *(const bf16x8*)&As[(ar + m * 16) * 32 + koff];
    #pragma unroll
    for (int n = 0; n < 4; n++) bfr[n] = *(const bf16x8*)&Bs[(br + n * 16) * 32 + koff];
    #pragma unroll
    for (int m = 0; m < 4; m++)
      #pragma unroll
      for (int n = 0; n < 4; n++)
        acc[m][n] = __builtin_amdgcn_mfma_f32_16x16x32_bf16(af[m], bfr[n], acc[m][n], 0, 0, 0);
    __syncthreads();
  }

  int crow0 = wr * 64 + (lane >> 4) * 4;
  int ccol0 = wc * 64 + (lane & 15);
  #pragma unroll
  for (int m = 0; m < 4; m++)
    #pragma unroll
    for (int n = 0; n < 4; n++) {
      int nn = bn + ccol0 + n * 16;
      #pragma unroll
      for (int r = 0; r < 4; r++) {
        int mm = bm + crow0 + m * 16 + r;
        C[(size_t)mm * N + nn] = acc[m][n][r];
      }
    }
}

// ---------------- GLA pass A (MFMA): Gc cumsum + Tc bf16 as [v][k] --------
__global__ __launch_bounds__(256) void gla_passA_k(
    const short* __restrict__ ksb, const short* __restrict__ vbb,
    const float* __restrict__ g, float* __restrict__ Gc, short* __restrict__ TcB)
{
  int bx = blockIdx.x;             // bkvh*NCH + c
  int c = bx & 31;
  int bkvh = bx >> 5;
  __shared__ float Gs[64][128];
  __shared__ short KgT[128 * 64];
  __shared__ short VT[128 * 64];
  size_t rowbase = ((size_t)bkvh * SS + c * 64) * 128;
  int tid = threadIdx.x, w = tid >> 6, l = tid & 63, gi = l >> 4;

  {
    int j = tid >> 2, d0 = (tid & 3) * 32;
    const float4* g4 = (const float4*)(g + rowbase + j * 128 + d0);
    float4* gs4 = (float4*)&Gs[j][d0];
    #pragma unroll
    for (int u = 0; u < 8; u++) gs4[u] = g4[u];
  }
  __syncthreads();
  if (tid < 128) {
    float run = 0.f;
    for (int j = 0; j < 64; j++) { run += Gs[j][tid]; Gs[j][tid] = run; }
  }
  __syncthreads();
  {
    int j = tid >> 2, d0 = (tid & 3) * 32;
    float4* gc4 = (float4*)(Gc + rowbase + j * 128 + d0);
    const float4* gs4 = (const float4*)&Gs[j][d0];
    #pragma unroll
    for (int u = 0; u < 8; u++) gc4[u] = gs4[u];
  }
  {
    int j = tid >> 2, d0 = (tid & 3) * 32;
    const bf16x8* k8 = (const bf16x8*)(ksb + rowbase + j * 128 + d0);
    const bf16x8* v8 = (const bf16x8*)(vbb + rowbase + j * 128 + d0);
    #pragma unroll
    for (int u = 0; u < 4; u++) {
      bf16x8 kv = k8[u], vv = v8[u];
      #pragma unroll
      for (int e = 0; e < 8; e++) {
        int d = d0 + u * 8 + e;
        float kg = bf2f(kv[e]) * __expf(Gs[63][d] - Gs[j][d]);
        lds_w16_swz(KgT, d, 64, j, f2bf(kg));
        lds_w16_swz(VT, d, 64, j, vv[e]);
      }
    }
  }
  __syncthreads();
  // Tc[vv][kk] = sum_j V[j][vv] * Kg[j][kk]; wave w owns vv in [32w,32w+32)
  f32x4 acc[2][8];
  #pragma unroll
  for (int m = 0; m < 2; m++)
    #pragma unroll
    for (int n = 0; n < 8; n++) acc[m][n] = (f32x4){0.f, 0.f, 0.f, 0.f};
  #pragma unroll
  for (int k0i = 0; k0i < 2; k0i++) {
    int k0 = k0i * 32 + gi * 8;
    bf16x8 af[2];
    #pragma unroll
    for (int m = 0; m < 2; m++) af[m] = ldsA(VT, 32 * w + 16 * m + (l & 15), 64, k0);
    #pragma unroll
    for (int n = 0; n < 8; n++) {
      bf16x8 bfr = ldsA(KgT, 16 * n + (l & 15), 64, k0);
      #pragma unroll
      for (int m = 0; m < 2; m++)
        acc[m][n] = __builtin_amdgcn_mfma_f32_16x16x32_bf16(af[m], bfr, acc[m][n], 0, 0, 0);
    }
  }
  size_t tbase = (size_t)bx * 16384;
  #pragma unroll
  for (int m = 0; m < 2; m++)
    #pragma unroll
    for (int n = 0; n < 8; n++)
      #pragma unroll
      for (int r = 0; r < 4; r++) {
        int vv = 32 * w + 16 * m + 4 * gi + r;
        int kk = 16 * n + (l & 15);
        TcB[tbase + (size_t)vv * 128 + kk] = f2bf(acc[m][n][r]);
      }
}

// ---------------- GLA pass B: scan; TcB bf16 [v][k]; writes hT bf16 -------
__global__ __launch_bounds__(256) void gla_passB_k(
    const short* __restrict__ TcB, const float* __restrict__ Gc,
    short* __restrict__ hT)
{
  int id = blockIdx.x * 256 + threadIdx.x; // (bkvh, v, k)
  int bkvh = id >> 14;
  int vk = id & 16383;
  int kk = vk & 127;
  float h = 0.f;
  for (int c = 0; c < NCH; ++c) {
    size_t cb = ((size_t)(bkvh * NCH + c) << 14);
    hT[cb + vk] = f2bf(h);
    float gl = Gc[((size_t)bkvh * SS + c * 64 + 63) * 128 + kk];
    h = h * __expf(gl) + bf2f(TcB[cb + vk]);
  }
}

// ---------------- GLA pass C (MFMA): o = tril(qe keT) v + qe h ------------
__global__ __launch_bounds__(256) void gla_passC_k(
    const short* __restrict__ qsm, const short* __restrict__ ksm,
    const short* __restrict__ vbb, const float* __restrict__ Gc,
    const short* __restrict__ hT, short* __restrict__ olin)
{
  int bx = blockIdx.x;            // (b*H+h)*NCH + c
  int c = bx & 31;
  int bh = bx >> 5;
  int b = bh >> 4, hq = bh & 15;
  int bkvh = b * HKVV + (hq >> 2);
  __shared__ short QeB[64 * 128];
  __shared__ short KeB[64 * 128];  // first 4096 reused as AmB after B1
  __shared__ short VtB[128 * 64];
  int tid = threadIdx.x, w = tid >> 6, l = tid & 63, g = l >> 4;
  size_t qrow = ((size_t)bh * SS + c * 64) * 128;
  size_t krow = ((size_t)bkvh * SS + c * 64) * 128;

  const short* hTb = hT + (((size_t)(bkvh * NCH + c)) << 14);
  bf16x8 hB[4][2];
  #pragma unroll
  for (int k0i = 0; k0i < 4; k0i++)
    #pragma unroll
    for (int nt = 0; nt < 2; nt++)
      hB[k0i][nt] = *(const bf16x8*)(hTb + (size_t)(32 * w + 16 * nt + (l & 15)) * 128 + k0i * 32 + g * 8);

  {
    int j = tid >> 2, d0 = (tid & 3) * 32;
    const bf16x8* q8 = (const bf16x8*)(qsm + qrow + j * 128 + d0);
    const bf16x8* k8 = (const bf16x8*)(ksm + krow + j * 128 + d0);
    const bf16x8* v8 = (const bf16x8*)(vbb + krow + j * 128 + d0);
    const float* gp = Gc + krow + j * 128 + d0;
    float gcv[32];
    #pragma unroll
    for (int u = 0; u < 8; u++) {
      float4 t = ((const float4*)gp)[u];
      gcv[4 * u] = t.x; gcv[4 * u + 1] = t.y; gcv[4 * u + 2] = t.z; gcv[4 * u + 3] = t.w;
    }
    #pragma unroll
    for (int u = 0; u < 4; u++) {
      bf16x8 qv = q8[u], kv = k8[u], vv = v8[u];
      #pragma unroll
      for (int e = 0; e < 8; e++) {
        int idx = u * 8 + e, d = d0 + idx;
        float eg = __expf(gcv[idx]);
        lds_w16_swz(QeB, j, 128, d, f2bf(bf2f(qv[e]) * eg));
        lds_w16_swz(KeB, j, 128, d, f2bf(bf2f(kv[e]) / eg));
        lds_w16_swz(VtB, d, 64, j, vv[e]);
      }
    }
  }
  __syncthreads(); // B0

  f32x4 acc1[4];
  #pragma unroll
  for (int m = 0; m < 4; m++) acc1[m] = (f32x4){0.f, 0.f, 0.f, 0.f};
  #pragma unroll
  for (int k0i = 0; k0i < 4; k0i++) {
    int k0 = k0i * 32 + g * 8;
    bf16x8 bk = ldsA(KeB, 16 * w + (l & 15), 128, k0);
    #pragma unroll
    for (int m = 0; m < 4; m++) {
      bf16x8 af = ldsA(QeB, 16 * m + (l & 15), 128, k0);
      acc1[m] = __builtin_amdgcn_mfma_f32_16x16x32_bf16(af, bk, acc1[m], 0, 0, 0);
    }
  }
  __syncthreads(); // B1
  short* AmB = KeB;
  #pragma unroll
  for (int m = 0; m < 4; m++)
    #pragma unroll
    for (int r = 0; r < 4; r++) {
      int i = 16 * m + 4 * g + r;
      int j = 16 * w + (l & 15);
      float val = (j <= i) ? acc1[m][r] : 0.f;
      lds_w16_swz(AmB, i, 64, j, f2bf(val));
    }
  __syncthreads(); // B2

  f32x4 acc[4][2];
  #pragma unroll
  for (int m = 0; m < 4; m++)
    #pragma unroll
    for (int nt = 0; nt < 2; nt++) acc[m][nt] = (f32x4){0.f, 0.f, 0.f, 0.f};
  #pragma unroll
  for (int k0i = 0; k0i < 2; k0i++) {
    int k0 = k0i * 32 + g * 8;
    bf16x8 bfr[2];
    #pragma unroll
    for (int nt = 0; nt < 2; nt++) bfr[nt] = ldsA(VtB, 32 * w + 16 * nt + (l & 15), 64, k0);
    #pragma unroll
    for (int m = 0; m < 4; m++) {
      bf16x8 af = ldsA(AmB, 16 * m + (l & 15), 64, k0);
      #pragma unroll
      for (int nt = 0; nt < 2; nt++)
        acc[m][nt] = __builtin_amdgcn_mfma_f32_16x16x32_bf16(af, bfr[nt], acc[m][nt], 0, 0, 0);
    }
  }
  #pragma unroll
  for (int k0i = 0; k0i < 4; k0i++) {
    int k0 = k0i * 32 + g * 8;
    #pragma unroll
    for (int m = 0; m < 4; m++) {
      bf16x8 af = ldsA(QeB, 16 * m + (l & 15), 128, k0);
      #pragma unroll
      for (int nt = 0; nt < 2; nt++)
        acc[m][nt] = __builtin_amdgcn_mfma_f32_16x16x32_bf16(af, hB[k0i][nt], acc[m][nt], 0, 0, 0);
    }
  }
  #pragma unroll
  for (int m = 0; m < 4; m++)
    #pragma unroll
    for (int nt = 0; nt < 2; nt++)
      #pragma unroll
      for (int r = 0; r < 4; r++) {
        int i = 16 * m + 4 * g + r, d = 32 * w + 16 * nt + (l & 15);
        olin[qrow + (size_t)i * 128 + d] = f2bf(acc[m][nt][r]);
      }
}

// ---------------- windowed attention (MFMA) + mix -> bf16 (B,S,H*D) -------
__global__ __launch_bounds__(256) void win_attn_k(
    const short* __restrict__ sqb, const short* __restrict__ skb,
    const short* __restrict__ vb, const short* __restrict__ olin,
    short* __restrict__ obf)
{
  int bx = blockIdx.x;            // (b*H+h)*NBLK + n
  int n = bx & 31;
  int bh = bx >> 5;
  int b = bh >> 4, hq = bh & 15;
  int bkvh = b * HKVV + (hq >> 2);
  __shared__ short Qs[64 * 128];   // then P (bf16)
  __shared__ short Ks[128 * 128];  // then V^T (bf16)
  __shared__ float wred[2][4][64];
  int tid = threadIdx.x, w = tid >> 6, l = tid & 63, g = l >> 4;
  const short* qg = sqb + ((size_t)bh * SS + n * 64) * 128;
  const short* kg = skb + (size_t)bkvh * SS * 128 + (ptrdiff_t)(n - 1) * 64 * 128;

  for (int c0 = w * 64; c0 < 1024; c0 += 256) {
    int cc = c0 + l, row = cc >> 4;
    int gb = (cc << 4) ^ ((row & 7) << 4);
    gld_lds16((const short*)((const char*)qg + gb), Qs + c0 * 8);
  }
  for (int c0 = w * 64; c0 < 2048; c0 += 256) {
    int cc = c0 + l, row = cc >> 4;
    int gb = (cc << 4) ^ ((row & 7) << 4);
    gld_lds16((const short*)((const char*)kg + gb), Ks + c0 * 8);
  }
  __syncthreads(); // B0

  f32x4 acc[4][2];
  #pragma unroll
  for (int m = 0; m < 4; m++)
    #pragma unroll
    for (int nt = 0; nt < 2; nt++) acc[m][nt] = (f32x4){0.f, 0.f, 0.f, 0.f};
  #pragma unroll
  for (int k0i = 0; k0i < 4; k0i++) {
    int k0 = k0i * 32 + g * 8;
    bf16x8 bfr[2];
    #pragma unroll
    for (int nt = 0; nt < 2; nt++) bfr[nt] = ldsA(Ks, 32 * w + 16 * nt + (l & 15), 128, k0);
    #pragma unroll
    for (int m = 0; m < 4; m++) {
      bf16x8 af = ldsA(Qs, 16 * m + (l & 15), 128, k0);
      #pragma unroll
      for (int nt = 0; nt < 2; nt++)
        acc[m][nt] = __builtin_amdgcn_mfma_f32_16x16x32_bf16(af, bfr[nt], acc[m][nt], 0, 0, 0);
    }
  }

  const float scale = 0.08838834764831845f;
  float mx[4][4];
  #pragma unroll
  for (int m = 0; m < 4; m++)
    #pragma unroll
    for (int r = 0; r < 4; r++) mx[m][r] = -1e30f;
  #pragma unroll
  for (int m = 0; m < 4; m++)
    #pragma unroll
    for (int nt = 0; nt < 2; nt++)
      #pragma unroll
      for (int r = 0; r < 4; r++) {
        int i = 16 * m + 4 * g + r;
        int j = 32 * w + 16 * nt + (l & 15);
        int kp = (n - 1) * 64 + j;
        bool valid = (j >= i) && (j <= i + 64) && (kp >= 0);
        float sc = valid ? acc[m][nt][r] * scale : -1e30f;
        acc[m][nt][r] = sc;
        mx[m][r] = fmaxf(mx[m][r], sc);
      }
  #pragma unroll
  for (int m = 0; m < 4; m++)
    #pragma unroll
    for (int r = 0; r < 4; r++) {
      #pragma unroll
      for (int msk = 1; msk < 16; msk <<= 1) mx[m][r] = fmaxf(mx[m][r], __shfl_xor(mx[m][r], msk));
    }
  if ((l & 15) == 0)
    #pragma unroll
    for (int m = 0; m < 4; m++)
      #pragma unroll
      for (int r = 0; r < 4; r++) wred[0][w][16 * m + 4 * g + r] = mx[m][r];
  __syncthreads(); // B1

  float mrow[4][4], sm[4][4];
  #pragma unroll
  for (int m = 0; m < 4; m++)
    #pragma unroll
    for (int r = 0; r < 4; r++) {
      int i = 16 * m + 4 * g + r;
      mrow[m][r] = fmaxf(fmaxf(wred[0][0][i], wred[0][1][i]), fmaxf(wred[0][2][i], wred[0][3][i]));
      sm[m][r] = 0.f;
    }
  #pragma unroll
  for (int m = 0; m < 4; m++)
    #pragma unroll
    for (int nt = 0; nt < 2; nt++)
      #pragma unroll
      for (int r = 0; r < 4; r++) {
        float p = __expf(acc[m][nt][r] - mrow[m][r]);
        acc[m][nt][r] = p;
        sm[m][r] += p;
      }
  #pragma unroll
  for (int m = 0; m < 4; m++)
    #pragma unroll
    for (int r = 0; r < 4; r++) {
      #pragma unroll
      for (int msk = 1; msk < 16; msk <<= 1) sm[m][r] += __shfl_xor(sm[m][r], msk);
    }
  if ((l & 15) == 0)
    #pragma unroll
    for (int m = 0; m < 4; m++)
      #pragma unroll
      for (int r = 0; r < 4; r++) wred[1][w][16 * m + 4 * g + r] = sm[m][r];
  __syncthreads(); // B2

  #pragma unroll
  for (int m = 0; m < 4; m++)
    #pragma unroll
    for (int r = 0; r < 4; r++) {
      int i = 16 * m + 4 * g + r;
      float s = wred[1][0][i] + wred[1][1][i] + wred[1][2][i] + wred[1][3][i];
      float inv = 1.0f / s;
      #pragma unroll
      for (int nt = 0; nt < 2; nt++) {
        int j = 32 * w + 16 * nt + (l & 15);
        lds_w16_swz(Qs, i, 128, j, f2bf(acc[m][nt][r] * inv));
      }
    }
  {
    int j = tid >> 1, dh = (tid & 1) * 64;
    int kp = (n - 1) * 64 + j;
    const short* vrow = vb + ((size_t)bkvh * SS + kp) * 128 + dh;
    #pragma unroll
    for (int u = 0; u < 8; u++) {
      bf16x8 vv;
      if (kp >= 0) vv = *(const bf16x8*)(vrow + u * 8);
      else vv = (bf16x8){0, 0, 0, 0, 0, 0, 0, 0};
      #pragma unroll
      for (int i2 = 0; i2 < 8; i2++)
        lds_w16_swz(Ks, dh + u * 8 + i2, 128, j, vv[i2]);
    }
  }
  __syncthreads(); // B3

  f32x4 o[4][2];
  #pragma unroll
  for (int m = 0; m < 4; m++)
    #pragma unroll
    for (int nt = 0; nt < 2; nt++) o[m][nt] = (f32x4){0.f, 0.f, 0.f, 0.f};
  #pragma unroll
  for (int k0i = 0; k0i < 4; k0i++) {
    int k0 = k0i * 32 + g * 8;
    bf16x8 bfr[2];
    #pragma unroll
    for (int nt = 0; nt < 2; nt++) bfr[nt] = ldsA(Ks, 32 * w + 16 * nt + (l & 15), 128, k0);
    #pragma unroll
    for (int m = 0; m < 4; m++) {
      bf16x8 af = ldsA(Qs, 16 * m + (l & 15), 128, k0);
      #pragma unroll
      for (int nt = 0; nt < 2; nt++)
        o[m][nt] = __builtin_amdgcn_mfma_f32_16x16x32_bf16(af, bfr[nt], o[m][nt], 0, 0, 0);
    }
  }
  #pragma unroll
  for (int m = 0; m < 4; m++)
    #pragma unroll
    for (int nt = 0; nt < 2; nt++)
      #pragma unroll
      for (int r = 0; r < 4; r++) {
        int i = 16 * m + 4 * g + r, d = 32 * w + 16 * nt + (l & 15);
        float ol = bf2f(olin[((size_t)bh * SS + n * 64 + i) * 128 + d]);
        float val = 0.5f * o[m][nt][r] + 0.5f * ol;
        obf[((size_t)(b * SS + n * 64 + i)) * HIDN + hq * 128 + d] = f2bf(val);
      }
}

// --------------------------------------------------------------------------
extern "C" void kernel_launch(void* const* d_in, const int* in_sizes, int n_in,
                              void* d_out, int out_size, void* d_ws, size_t ws_size,
                              hipStream_t stream)
{
  const float* hs = (const float*)d_in[0];
  const int*  pos = (const int*)d_in[1];
  const float* Wq = (const float*)d_in[2];
  const float* bq = (const float*)d_in[3];
  const float* Wk = (const float*)d_in[4];
  const float* bk = (const float*)d_in[5];
  const float* Wv = (const float*)d_in[6];
  const float* bv = (const float*)d_in[7];
  const float* Wo = (const float*)d_in[8];
  float* out = (float*)d_out;

  float* w = (float*)d_ws;
  const size_t QSZ = (size_t)BB * HH * SS * DD;         // 8388608
  const size_t KSZ = (size_t)BB * HKVV * SS * DD;       // 2097152
  const size_t TSZ = (size_t)BB * HKVV * NCH * DD * DD; // 4194304
  short* hs_bf = (short*)w; w += QSZ / 2;
  float* qbuf  = w; w += QSZ;
  float* kbuf  = w; w += KSZ;
  short* qsm   = (short*)w; w += QSZ / 2;
  short* sqb   = (short*)w; w += QSZ / 2;
  short* ksm   = (short*)w; w += KSZ / 2;
  short* skb   = (short*)w; w += KSZ / 2;
  short* vb    = (short*)w; w += KSZ / 2;
  float* gbuf  = w; w += KSZ;
  float* Gc    = w; w += KSZ;
  float* Tc    = w; w += TSZ;             // bf16 TcB in front half; obf aliases after passB
  short* hT    = (short*)w; w += TSZ / 2;
  short* olin  = (short*)w; w += QSZ / 2;
  float* ct    = w; w += (size_t)SS * 64;
  float* st    = w; w += (size_t)SS * 64;
  short* wo_bf = (short*)w; w += (size_t)HIDN * HIDN / 2;
  short* wqkv_bf = (short*)w; w += (size_t)3072 * HIDN / 2;

  short* TcB = (short*)Tc;   // TSZ bf16 elems = front half of Tc region
  short* obf = (short*)Tc;   // written by win_attn after TcB is dead

  dim3 blk(256);
  const int M = BB * SS; // 4096

  // casts + rope table (one kernel)
  cast_all_k<<<dim3(18944), blk, 0, stream>>>(hs, Wq, Wk, Wv, Wo, pos,
                                              hs_bf, wqkv_bf, wo_bf, ct, st);

  // fused QKV projection (r4/r9-proven minimal epilogue, VGPR 76)
  qkv_gemm_k<<<dim3(768), blk, 0, stream>>>(hs_bf, wqkv_bf, bq, bk, bv,
                                            qbuf, kbuf, vb);

  // softmax + rope + gate
  prep_k<<<dim3((BB * HH * SS + BB * HKVV * SS) / 8), blk, 0, stream>>>(
      qbuf, kbuf, ct, st, qsm, sqb, ksm, skb, gbuf);

  gla_passA_k<<<dim3(BB * HKVV * NCH), blk, 0, stream>>>(ksm, vb, gbuf, Gc, TcB);
  gla_passB_k<<<dim3(BB * HKVV * DD * DD / 256), blk, 0, stream>>>(TcB, Gc, hT);
  gla_passC_k<<<dim3(BB * HH * NCH), blk, 0, stream>>>(qsm, ksm, vb, Gc, hT, olin);

  win_attn_k<<<dim3(BB * HH * NBLK), blk, 0, stream>>>(sqb, skb, vb, olin, obf);

  mfma_gemm_bt<<<dim3(512), blk, 0, stream>>>(obf, wo_bf, out, M, HIDN, HIDN, 16, 64);
}

// Round 12
// 224.925 us; speedup vs baseline: 1.1739x; 1.0195x over previous
//
#include <hip/hip_runtime.h>
#include <hip/hip_bf16.h>
#include <math.h>

#define BB   2
#define SS   2048
#define HIDN 2048
#define HH   16
#define HKVV 4
#define DD   128
#define NCH  32   // S/CHUNK
#define CHK  64
#define NBLK 32   // S/WIN

typedef __attribute__((ext_vector_type(8))) short bf16x8;
typedef __attribute__((ext_vector_type(4))) float f32x4;

__device__ __forceinline__ short f2bf(float x)
{
  __hip_bfloat16 h = __float2bfloat16(x);
  return *(short*)&h;
}
__device__ __forceinline__ float bf2f(short x)
{
  return __uint_as_float(((uint)(ushort)x) << 16);
}

__device__ __forceinline__ void gld_lds16(const short* g, short* lds)
{
  __builtin_amdgcn_global_load_lds(
      (const __attribute__((address_space(1))) void*)g,
      (__attribute__((address_space(3))) void*)lds, 16, 0, 0);
}

// swizzled LDS helpers: byte ^= ((row&7)<<4) within each 8-row stripe
__device__ __forceinline__ bf16x8 ldsA(const short* base, int row, int rs, int ks)
{
  int byte = (row * rs + ks) * 2;
  byte ^= ((row & 7) << 4);
  __builtin_assume((byte & 15) == 0);
  return *(const bf16x8*)((const char*)base + byte);
}
__device__ __forceinline__ void lds_w16_swz(short* base, int row, int rs, int ks, short v)
{
  int byte = (row * rs + ks) * 2;
  byte ^= ((row & 7) << 4);
  *(short*)((char*)base + byte) = v;
}

// ---------------- combined fp32->bf16 cast + rope table -------------------
__global__ __launch_bounds__(256) void cast_all_k(
    const float* __restrict__ hs, const float* __restrict__ wq,
    const float* __restrict__ wk, const float* __restrict__ wv,
    const float* __restrict__ wo, const int* __restrict__ pos,
    short* __restrict__ hs_bf, short* __restrict__ wqkv_bf, short* __restrict__ wo_bf,
    float* __restrict__ ct, float* __restrict__ st)
{
  int i = blockIdx.x * 256 + threadIdx.x;   // f4 index, total 4718592 + rope 131072
  if (i >= 4718592) {
    int id = i - 4718592;                    // SS*64 entries
    int s = id >> 6, fi = id & 63;
    double inv = pow(1.0e6, -(double)(2 * fi) / 128.0);
    double ang = (double)pos[s] * inv;
    ct[id] = (float)cos(ang);
    st[id] = (float)sin(ang);
    return;
  }
  const float* src; short* dst; int off;
  if (i < 2097152)       { src = hs; dst = hs_bf;            off = i; }
  else if (i < 3145728)  { src = wq; dst = wqkv_bf;          off = i - 2097152; }
  else if (i < 3407872)  { src = wk; dst = wqkv_bf + 4194304; off = i - 3145728; }
  else if (i < 3670016)  { src = wv; dst = wqkv_bf + 5242880; off = i - 3407872; }
  else                   { src = wo; dst = wo_bf;            off = i - 3670016; }
  const float4 v = ((const float4*)src)[off];
  short4 o;
  o.x = f2bf(v.x); o.y = f2bf(v.y); o.z = f2bf(v.z); o.w = f2bf(v.w);
  ((short4*)dst)[off] = o;
}

__device__ __forceinline__ float logsigf(float x)
{
  return (x >= 0.f) ? -log1pf(expf(-x)) : x - log1pf(expf(x));
}

// ---------------- fused QKV GEMM: minimal epilogue (r4/r9-proven) ---------
__global__ __launch_bounds__(256) void qkv_gemm_k(
    const short* __restrict__ A, const short* __restrict__ Bt,
    const float* __restrict__ bq, const float* __restrict__ bk,
    const float* __restrict__ bv,
    float* __restrict__ qbuf, float* __restrict__ kbuf, short* __restrict__ vb)
{
  const int K = HIDN, GX = 24;
  __shared__ short As[128 * 32];
  __shared__ short Bs[128 * 32];
  int orig = blockIdx.x;
  int wg = ((orig & 7) * 96) + (orig >> 3);  // nwg=768, bijective XCD swizzle
  int bm = (wg / GX) * 128, bn = (wg % GX) * 128;
  int tid = threadIdx.x;
  int wave = tid >> 6, lane = tid & 63;
  int wr = wave >> 1, wc = wave & 1;
  int l15 = lane & 15, g4i = lane >> 4;

  f32x4 acc[4][4];
  #pragma unroll
  for (int m = 0; m < 4; m++)
    #pragma unroll
    for (int n = 0; n < 4; n++) acc[m][n] = (f32x4){0.f, 0.f, 0.f, 0.f};

  int srow = lane >> 2;
  int scol = (lane & 3) * 8;
  const short* Abase = A + (size_t)bm * K;
  const short* Bbase = Bt + (size_t)bn * K;

  for (int k0 = 0; k0 < K; k0 += 32) {
    #pragma unroll
    for (int t = wave; t < 8; t += 4) {
      gld_lds16(Abase + (size_t)(t * 16 + srow) * K + k0 + scol, &As[t * 512]);
      gld_lds16(Bbase + (size_t)(t * 16 + srow) * K + k0 + scol, &Bs[t * 512]);
    }
    __syncthreads();
    int koff = g4i * 8;
    int ar = wr * 64 + l15;
    int br = wc * 64 + l15;
    bf16x8 af[4], bfr[4];
    #pragma unroll
    for (int m = 0; m < 4; m++) af[m] = *(const bf16x8*)&As[(ar + m * 16) * 32 + koff];
    #pragma unroll
    for (int n = 0; n < 4; n++) bfr[n] = *(const bf16x8*)&Bs[(br + n * 16) * 32 + koff];
    #pragma unroll
    for (int m = 0; m < 4; m++)
      #pragma unroll
      for (int n = 0; n < 4; n++)
        acc[m][n] = __builtin_amdgcn_mfma_f32_16x16x32_bf16(af[m], bfr[n], acc[m][n], 0, 0, 0);
    __syncthreads();
  }

  int proj = (bn < 2048) ? 0 : ((bn < 2560) ? 1 : 2);
  int nbase = (proj == 0) ? bn : ((proj == 1) ? bn - 2048 : bn - 2560);
  const float* bias = (proj == 0) ? bq : ((proj == 1) ? bk : bv);
  float* fdst = (proj == 0) ? qbuf : kbuf;
  int NHp = (proj == 0) ? HH : HKVV;

  int crow0 = wr * 64 + g4i * 4;
  int ccol0 = wc * 64 + l15;
  #pragma unroll
  for (int m = 0; m < 4; m++) {
    #pragma unroll
    for (int n = 0; n < 4; n++) {
      int nn = nbase + ccol0 + n * 16;
      float bvl = bias[nn];
      int hh = nn >> 7, d = nn & 127;
      #pragma unroll
      for (int r = 0; r < 4; r++) {
        int mm = bm + crow0 + m * 16 + r;
        int b = mm >> 11, s = mm & 2047;
        float val = acc[m][n][r] + bvl;
        size_t idx = (size_t)((b * NHp + hh) * SS + s) * DD + d;
        if (proj == 2) vb[idx] = f2bf(val);
        else fdst[idx] = val;
      }
    }
  }
}

// ---------------- prep: softmax + rope (+gate for k) from f32 q/k ---------
__global__ __launch_bounds__(256) void prep_k(
    const float* __restrict__ qbuf, const float* __restrict__ kbuf,
    const float* __restrict__ ct, const float* __restrict__ st,
    short* __restrict__ qsm, short* __restrict__ sqb,
    short* __restrict__ ksm, short* __restrict__ skb, float* __restrict__ gbuf)
{
  int rowid = blockIdx.x * 8 + (threadIdx.x >> 5);
  int l32 = threadIdx.x & 31;
  bool isq = rowid < (BB * HH * SS);
  int row = isq ? rowid : rowid - BB * HH * SS;
  int s = row & (SS - 1);
  size_t base = (size_t)row * 128;
  int c = l32 * 4;
  const float* src = isq ? qbuf : kbuf;
  float4 x4 = *(const float4*)(src + base + c);
  float x0 = x4.x, x1 = x4.y, x2 = x4.z, x3 = x4.w;

  float p0 = __shfl_xor(x0, 16), p1 = __shfl_xor(x1, 16);
  float p2 = __shfl_xor(x2, 16), p3 = __shfl_xor(x3, 16);
  int f = c & 63;
  float4 cv = *(const float4*)(ct + (size_t)s * 64 + f);
  float4 sv = *(const float4*)(st + (size_t)s * 64 + f);
  float sgn = (c < 64) ? -1.f : 1.f;
  short4 r4;
  r4.x = f2bf(x0 * cv.x + sgn * p0 * sv.x);
  r4.y = f2bf(x1 * cv.y + sgn * p1 * sv.y);
  r4.z = f2bf(x2 * cv.z + sgn * p2 * sv.z);
  r4.w = f2bf(x3 * cv.w + sgn * p3 * sv.w);
  *(short4*)((isq ? sqb : skb) + base + c) = r4;

  if (!isq) {
    float4 gv = make_float4(logsigf(x0) * (1.0f / 16.0f), logsigf(x1) * (1.0f / 16.0f),
                            logsigf(x2) * (1.0f / 16.0f), logsigf(x3) * (1.0f / 16.0f));
    *(float4*)(gbuf + base + c) = gv;
  }

  float m = fmaxf(fmaxf(x0, x1), fmaxf(x2, x3));
  #pragma unroll
  for (int msk = 1; msk < 32; msk <<= 1) m = fmaxf(m, __shfl_xor(m, msk));
  float e0 = __expf(x0 - m), e1 = __expf(x1 - m), e2 = __expf(x2 - m), e3 = __expf(x3 - m);
  float sum = e0 + e1 + e2 + e3;
  #pragma unroll
  for (int msk = 1; msk < 32; msk <<= 1) sum += __shfl_xor(sum, msk);
  float inv = 1.0f / sum;
  short4 o;
  o.x = f2bf(e0 * inv); o.y = f2bf(e1 * inv); o.z = f2bf(e2 * inv); o.w = f2bf(e3 * inv);
  *(short4*)((isq ? qsm : ksm) + base + c) = o;
}

// ---------------- bf16 MFMA GEMM (plain store), 1D grid XCD-swizzled ------
__global__ __launch_bounds__(256) void mfma_gemm_bt(
    const short* __restrict__ A, const short* __restrict__ Bt,
    float* __restrict__ C, int M, int N, int K, int gx, int q0)
{
  __shared__ short As[128 * 32];
  __shared__ short Bs[128 * 32];
  int orig = blockIdx.x;
  int wg = ((orig & 7) * q0) + (orig >> 3);
  int bm = (wg / gx) * 128, bn = (wg % gx) * 128;
  int tid = threadIdx.x;
  int wave = tid >> 6, lane = tid & 63;
  int wr = wave >> 1, wc = wave & 1;

  f32x4 acc[4][4];
  #pragma unroll
  for (int m = 0; m < 4; m++)
    #pragma unroll
    for (int n = 0; n < 4; n++) acc[m][n] = (f32x4){0.f, 0.f, 0.f, 0.f};

  int srow = lane >> 2;
  int scol = (lane & 3) * 8;
  const short* Abase = A + (size_t)bm * K;
  const short* Bbase = Bt + (size_t)bn * K;

  for (int k0 = 0; k0 < K; k0 += 32) {
    #pragma unroll
    for (int t = wave; t < 8; t += 4) {
      gld_lds16(Abase + (size_t)(t * 16 + srow) * K + k0 + scol, &As[t * 512]);
      gld_lds16(Bbase + (size_t)(t * 16 + srow) * K + k0 + scol, &Bs[t * 512]);
    }
    __syncthreads();
    int koff = (lane >> 4) * 8;
    int ar = wr * 64 + (lane & 15);
    int br = wc * 64 + (lane & 15);
    bf16x8 af[4], bfr[4];
    #pragma unroll
    for (int m = 0; m < 4; m++) af[m] = *(const bf16x8*)&As[(ar + m * 16) * 32 + koff];
    #pragma unroll
    for (int n = 0; n < 4; n++) bfr[n] = *(const bf16x8*)&Bs[(br + n * 16) * 32 + koff];
    #pragma unroll
    for (int m = 0; m < 4; m++)
      #pragma unroll
      for (int n = 0; n < 4; n++)
        acc[m][n] = __builtin_amdgcn_mfma_f32_16x16x32_bf16(af[m], bfr[n], acc[m][n], 0, 0, 0);
    __syncthreads();
  }

  int crow0 = wr * 64 + (lane >> 4) * 4;
  int ccol0 = wc * 64 + (lane & 15);
  #pragma unroll
  for (int m = 0; m < 4; m++)
    #pragma unroll
    for (int n = 0; n < 4; n++) {
      int nn = bn + ccol0 + n * 16;
      #pragma unroll
      for (int r = 0; r < 4; r++) {
        int mm = bm + crow0 + m * 16 + r;
        C[(size_t)mm * N + nn] = acc[m][n][r];
      }
    }
}

// ---------------- GLA pass A (MFMA): Gc cumsum + Tc bf16 as [v][k] --------
__global__ __launch_bounds__(256) void gla_passA_k(
    const short* __restrict__ ksb, const short* __restrict__ vbb,
    const float* __restrict__ g, float* __restrict__ Gc, short* __restrict__ TcB)
{
  int bx = blockIdx.x;             // bkvh*NCH + c
  int c = bx & 31;
  int bkvh = bx >> 5;
  __shared__ float Gs[64][128];
  __shared__ short KgT[128 * 64];
  __shared__ short VT[128 * 64];
  size_t rowbase = ((size_t)bkvh * SS + c * 64) * 128;
  int tid = threadIdx.x, w = tid >> 6, l = tid & 63, gi = l >> 4;

  {
    int j = tid >> 2, d0 = (tid & 3) * 32;
    const float4* g4 = (const float4*)(g + rowbase + j * 128 + d0);
    float4* gs4 = (float4*)&Gs[j][d0];
    #pragma unroll
    for (int u = 0; u < 8; u++) gs4[u] = g4[u];
  }
  __syncthreads();
  if (tid < 128) {
    float run = 0.f;
    for (int j = 0; j < 64; j++) { run += Gs[j][tid]; Gs[j][tid] = run; }
  }
  __syncthreads();
  {
    int j = tid >> 2, d0 = (tid & 3) * 32;
    float4* gc4 = (float4*)(Gc + rowbase + j * 128 + d0);
    const float4* gs4 = (const float4*)&Gs[j][d0];
    #pragma unroll
    for (int u = 0; u < 8; u++) gc4[u] = gs4[u];
  }
  {
    int j = tid >> 2, d0 = (tid & 3) * 32;
    const bf16x8* k8 = (const bf16x8*)(ksb + rowbase + j * 128 + d0);
    const bf16x8* v8 = (const bf16x8*)(vbb + rowbase + j * 128 + d0);
    #pragma unroll
    for (int u = 0; u < 4; u++) {
      bf16x8 kv = k8[u], vv = v8[u];
      #pragma unroll
      for (int e = 0; e < 8; e++) {
        int d = d0 + u * 8 + e;
        float kg = bf2f(kv[e]) * __expf(Gs[63][d] - Gs[j][d]);
        lds_w16_swz(KgT, d, 64, j, f2bf(kg));
        lds_w16_swz(VT, d, 64, j, vv[e]);
      }
    }
  }
  __syncthreads();
  f32x4 acc[2][8];
  #pragma unroll
  for (int m = 0; m < 2; m++)
    #pragma unroll
    for (int n = 0; n < 8; n++) acc[m][n] = (f32x4){0.f, 0.f, 0.f, 0.f};
  #pragma unroll
  for (int k0i = 0; k0i < 2; k0i++) {
    int k0 = k0i * 32 + gi * 8;
    bf16x8 af[2];
    #pragma unroll
    for (int m = 0; m < 2; m++) af[m] = ldsA(VT, 32 * w + 16 * m + (l & 15), 64, k0);
    #pragma unroll
    for (int n = 0; n < 8; n++) {
      bf16x8 bfr = ldsA(KgT, 16 * n + (l & 15), 64, k0);
      #pragma unroll
      for (int m = 0; m < 2; m++)
        acc[m][n] = __builtin_amdgcn_mfma_f32_16x16x32_bf16(af[m], bfr, acc[m][n], 0, 0, 0);
    }
  }
  size_t tbase = (size_t)bx * 16384;
  #pragma unroll
  for (int m = 0; m < 2; m++)
    #pragma unroll
    for (int n = 0; n < 8; n++)
      #pragma unroll
      for (int r = 0; r < 4; r++) {
        int vv = 32 * w + 16 * m + 4 * gi + r;
        int kk = 16 * n + (l & 15);
        TcB[tbase + (size_t)vv * 128 + kk] = f2bf(acc[m][n][r]);
      }
}

// ---------------- GLA pass B: scan; TcB bf16 [v][k]; writes hT bf16 -------
__global__ __launch_bounds__(256) void gla_passB_k(
    const short* __restrict__ TcB, const float* __restrict__ Gc,
    short* __restrict__ hT)
{
  int id = blockIdx.x * 256 + threadIdx.x; // (bkvh, v, k)
  int bkvh = id >> 14;
  int vk = id & 16383;
  int kk = vk & 127;
  float h = 0.f;
  for (int c = 0; c < NCH; ++c) {
    size_t cb = ((size_t)(bkvh * NCH + c) << 14);
    hT[cb + vk] = f2bf(h);
    float gl = Gc[((size_t)bkvh * SS + c * 64 + 63) * 128 + kk];
    h = h * __expf(gl) + bf2f(TcB[cb + vk]);
  }
}

// ---------------- FUSED GLA pass C + windowed attention -------------------
// Phase 1: o_lin = tril(qe keT) v + qe h  -> registers
// Phase 2: window attn on roped q/k, mix, store obf.
__global__ __launch_bounds__(256) void gla_win_k(
    const short* __restrict__ qsm, const short* __restrict__ ksm,
    const short* __restrict__ sqb, const short* __restrict__ skb,
    const short* __restrict__ vbb, const float* __restrict__ Gc,
    const short* __restrict__ hT, short* __restrict__ obf)
{
  int bx = blockIdx.x;            // (b*H+h)*NCH + c   (c == window block n)
  int c = bx & 31;
  int bh = bx >> 5;
  int b = bh >> 4, hq = bh & 15;
  int bkvh = b * HKVV + (hq >> 2);
  __shared__ short SA[64 * 128];   // QeB -> Qs -> P
  __shared__ short SB[64 * 128];   // KeB/AmB -> Ks rows 0-63 -> V^T rows 0-63
  __shared__ short SC[128 * 64];   // VtB -> Ks rows 64-127 -> V^T rows 64-127
  __shared__ float wred[2][4][64];
  int tid = threadIdx.x, w = tid >> 6, l = tid & 63, g = l >> 4;
  int l15 = l & 15;
  size_t qrow = ((size_t)bh * SS + c * 64) * 128;
  size_t krow = ((size_t)bkvh * SS + c * 64) * 128;

  // h^T B-fragments
  const short* hTb = hT + (((size_t)(bkvh * NCH + c)) << 14);
  bf16x8 hB[4][2];
  #pragma unroll
  for (int k0i = 0; k0i < 4; k0i++)
    #pragma unroll
    for (int nt = 0; nt < 2; nt++)
      hB[k0i][nt] = *(const bf16x8*)(hTb + (size_t)(32 * w + 16 * nt + l15) * 128 + k0i * 32 + g * 8);

  // ---- phase 1 staging: Qe, Ke, V^T ----
  {
    int j = tid >> 2, d0 = (tid & 3) * 32;
    const bf16x8* q8 = (const bf16x8*)(qsm + qrow + (size_t)j * 128 + d0);
    const bf16x8* k8 = (const bf16x8*)(ksm + krow + (size_t)j * 128 + d0);
    const bf16x8* v8 = (const bf16x8*)(vbb + krow + (size_t)j * 128 + d0);
    const float* gp = Gc + krow + (size_t)j * 128 + d0;
    float gcv[32];
    #pragma unroll
    for (int u = 0; u < 8; u++) {
      float4 t = ((const float4*)gp)[u];
      gcv[4 * u] = t.x; gcv[4 * u + 1] = t.y; gcv[4 * u + 2] = t.z; gcv[4 * u + 3] = t.w;
    }
    #pragma unroll
    for (int u = 0; u < 4; u++) {
      bf16x8 qv = q8[u], kv = k8[u], vv = v8[u];
      #pragma unroll
      for (int e = 0; e < 8; e++) {
        int idx = u * 8 + e, d = d0 + idx;
        float eg = __expf(gcv[idx]);
        lds_w16_swz(SA, j, 128, d, f2bf(bf2f(qv[e]) * eg));
        lds_w16_swz(SB, j, 128, d, f2bf(bf2f(kv[e]) / eg));
        lds_w16_swz(SC, d, 64, j, vv[e]);
      }
    }
  }
  __syncthreads(); // B0

  // A1 = qe * ke^T
  f32x4 acc1[4];
  #pragma unroll
  for (int m = 0; m < 4; m++) acc1[m] = (f32x4){0.f, 0.f, 0.f, 0.f};
  #pragma unroll
  for (int k0i = 0; k0i < 4; k0i++) {
    int k0 = k0i * 32 + g * 8;
    bf16x8 bk = ldsA(SB, 16 * w + l15, 128, k0);
    #pragma unroll
    for (int m = 0; m < 4; m++) {
      bf16x8 af = ldsA(SA, 16 * m + l15, 128, k0);
      acc1[m] = __builtin_amdgcn_mfma_f32_16x16x32_bf16(af, bk, acc1[m], 0, 0, 0);
    }
  }
  __syncthreads(); // B1
  #pragma unroll
  for (int m = 0; m < 4; m++)
    #pragma unroll
    for (int r = 0; r < 4; r++) {
      int i = 16 * m + 4 * g + r;
      int j = 16 * w + l15;
      float val = (j <= i) ? acc1[m][r] : 0.f;
      lds_w16_swz(SB, i, 64, j, f2bf(val));   // AmB over KeB
    }
  __syncthreads(); // B2

  // o_lin = Am * V + Qe * h  (held in registers)
  f32x4 olacc[4][2];
  #pragma unroll
  for (int m = 0; m < 4; m++)
    #pragma unroll
    for (int nt = 0; nt < 2; nt++) olacc[m][nt] = (f32x4){0.f, 0.f, 0.f, 0.f};
  #pragma unroll
  for (int k0i = 0; k0i < 2; k0i++) {
    int k0 = k0i * 32 + g * 8;
    bf16x8 bfr[2];
    #pragma unroll
    for (int nt = 0; nt < 2; nt++) bfr[nt] = ldsA(SC, 32 * w + 16 * nt + l15, 64, k0);
    #pragma unroll
    for (int m = 0; m < 4; m++) {
      bf16x8 af = ldsA(SB, 16 * m + l15, 64, k0);
      #pragma unroll
      for (int nt = 0; nt < 2; nt++)
        olacc[m][nt] = __builtin_amdgcn_mfma_f32_16x16x32_bf16(af, bfr[nt], olacc[m][nt], 0, 0, 0);
    }
  }
  #pragma unroll
  for (int k0i = 0; k0i < 4; k0i++) {
    int k0 = k0i * 32 + g * 8;
    #pragma unroll
    for (int m = 0; m < 4; m++) {
      bf16x8 af = ldsA(SA, 16 * m + l15, 128, k0);
      #pragma unroll
      for (int nt = 0; nt < 2; nt++)
        olacc[m][nt] = __builtin_amdgcn_mfma_f32_16x16x32_bf16(af, hB[k0i][nt], olacc[m][nt], 0, 0, 0);
    }
  }
  __syncthreads(); // B3: all phase-1 LDS reads done

  // ---- phase 2 staging: roped Q -> SA, roped K window -> SB/SC ----
  {
    const short* qg = sqb + qrow;
    const short* kg = skb + (size_t)bkvh * SS * 128 + (ptrdiff_t)(c - 1) * 64 * 128;
    for (int c0 = w * 64; c0 < 1024; c0 += 256) {
      int cc = c0 + l, row = cc >> 4;
      int gb = (cc << 4) ^ ((row & 7) << 4);
      gld_lds16((const short*)((const char*)qg + gb), SA + c0 * 8);
    }
    for (int c0 = w * 64; c0 < 2048; c0 += 256) {
      int cc = c0 + l, row = cc >> 4;
      int gb = (cc << 4) ^ ((row & 7) << 4);
      short* dst = (c0 < 1024) ? (SB + c0 * 8) : (SC + (c0 - 1024) * 8);
      gld_lds16((const short*)((const char*)kg + gb), dst);
    }
  }
  __syncthreads(); // B4

  // window QK^T
  f32x4 acc[4][2];
  #pragma unroll
  for (int m = 0; m < 4; m++)
    #pragma unroll
    for (int nt = 0; nt < 2; nt++) acc[m][nt] = (f32x4){0.f, 0.f, 0.f, 0.f};
  #pragma unroll
  for (int k0i = 0; k0i < 4; k0i++) {
    int k0 = k0i * 32 + g * 8;
    bf16x8 bfr[2];
    #pragma unroll
    for (int nt = 0; nt < 2; nt++) {
      int row = 32 * w + 16 * nt + l15;
      bfr[nt] = (row < 64) ? ldsA(SB, row, 128, k0) : ldsA(SC, row - 64, 128, k0);
    }
    #pragma unroll
    for (int m = 0; m < 4; m++) {
      bf16x8 af = ldsA(SA, 16 * m + l15, 128, k0);
      #pragma unroll
      for (int nt = 0; nt < 2; nt++)
        acc[m][nt] = __builtin_amdgcn_mfma_f32_16x16x32_bf16(af, bfr[nt], acc[m][nt], 0, 0, 0);
    }
  }

  const float scale = 0.08838834764831845f;
  float mx[4][4];
  #pragma unroll
  for (int m = 0; m < 4; m++)
    #pragma unroll
    for (int r = 0; r < 4; r++) mx[m][r] = -1e30f;
  #pragma unroll
  for (int m = 0; m < 4; m++)
    #pragma unroll
    for (int nt = 0; nt < 2; nt++)
      #pragma unroll
      for (int r = 0; r < 4; r++) {
        int i = 16 * m + 4 * g + r;
        int j = 32 * w + 16 * nt + l15;
        int kp = (c - 1) * 64 + j;
        bool valid = (j >= i) && (j <= i + 64) && (kp >= 0);
        float sc = valid ? acc[m][nt][r] * scale : -1e30f;
        acc[m][nt][r] = sc;
        mx[m][r] = fmaxf(mx[m][r], sc);
      }
  #pragma unroll
  for (int m = 0; m < 4; m++)
    #pragma unroll
    for (int r = 0; r < 4; r++) {
      #pragma unroll
      for (int msk = 1; msk < 16; msk <<= 1) mx[m][r] = fmaxf(mx[m][r], __shfl_xor(mx[m][r], msk));
    }
  if (l15 == 0)
    #pragma unroll
    for (int m = 0; m < 4; m++)
      #pragma unroll
      for (int r = 0; r < 4; r++) wred[0][w][16 * m + 4 * g + r] = mx[m][r];
  __syncthreads(); // B5

  float mrow[4][4], sm[4][4];
  #pragma unroll
  for (int m = 0; m < 4; m++)
    #pragma unroll
    for (int r = 0; r < 4; r++) {
      int i = 16 * m + 4 * g + r;
      mrow[m][r] = fmaxf(fmaxf(wred[0][0][i], wred[0][1][i]), fmaxf(wred[0][2][i], wred[0][3][i]));
      sm[m][r] = 0.f;
    }
  #pragma unroll
  for (int m = 0; m < 4; m++)
    #pragma unroll
    for (int nt = 0; nt < 2; nt++)
      #pragma unroll
      for (int r = 0; r < 4; r++) {
        float p = __expf(acc[m][nt][r] - mrow[m][r]);
        acc[m][nt][r] = p;
        sm[m][r] += p;
      }
  #pragma unroll
  for (int m = 0; m < 4; m++)
    #pragma unroll
    for (int r = 0; r < 4; r++) {
      #pragma unroll
      for (int msk = 1; msk < 16; msk <<= 1) sm[m][r] += __shfl_xor(sm[m][r], msk);
    }
  if (l15 == 0)
    #pragma unroll
    for (int m = 0; m < 4; m++)
      #pragma unroll
      for (int r = 0; r < 4; r++) wred[1][w][16 * m + 4 * g + r] = sm[m][r];
  __syncthreads(); // B6

  // write P over SA; stage V^T over SB/SC
  #pragma unroll
  for (int m = 0; m < 4; m++)
    #pragma unroll
    for (int r = 0; r < 4; r++) {
      int i = 16 * m + 4 * g + r;
      float s = wred[1][0][i] + wred[1][1][i] + wred[1][2][i] + wred[1][3][i];
      float inv = 1.0f / s;
      #pragma unroll
      for (int nt = 0; nt < 2; nt++) {
        int j = 32 * w + 16 * nt + l15;
        lds_w16_swz(SA, i, 128, j, f2bf(acc[m][nt][r] * inv));
      }
    }
  {
    int j = tid >> 1, dh = (tid & 1) * 64;
    int kp = (c - 1) * 64 + j;
    const short* vrow = vbb + ((size_t)bkvh * SS + kp) * 128 + dh;
    #pragma unroll
    for (int u = 0; u < 8; u++) {
      bf16x8 vv;
      if (kp >= 0) vv = *(const bf16x8*)(vrow + u * 8);
      else vv = (bf16x8){0, 0, 0, 0, 0, 0, 0, 0};
      #pragma unroll
      for (int i2 = 0; i2 < 8; i2++) {
        int row = dh + u * 8 + i2;
        if (row < 64) lds_w16_swz(SB, row, 128, j, vv[i2]);
        else lds_w16_swz(SC, row - 64, 128, j, vv[i2]);
      }
    }
  }
  __syncthreads(); // B7

  // PV + mix with register-held o_lin
  f32x4 o[4][2];
  #pragma unroll
  for (int m = 0; m < 4; m++)
    #pragma unroll
    for (int nt = 0; nt < 2; nt++) o[m][nt] = (f32x4){0.f, 0.f, 0.f, 0.f};
  #pragma unroll
  for (int k0i = 0; k0i < 4; k0i++) {
    int k0 = k0i * 32 + g * 8;
    bf16x8 bfr[2];
    #pragma unroll
    for (int nt = 0; nt < 2; nt++) {
      int row = 32 * w + 16 * nt + l15;
      bfr[nt] = (row < 64) ? ldsA(SB, row, 128, k0) : ldsA(SC, row - 64, 128, k0);
    }
    #pragma unroll
    for (int m = 0; m < 4; m++) {
      bf16x8 af = ldsA(SA, 16 * m + l15, 128, k0);
      #pragma unroll
      for (int nt = 0; nt < 2; nt++)
        o[m][nt] = __builtin_amdgcn_mfma_f32_16x16x32_bf16(af, bfr[nt], o[m][nt], 0, 0, 0);
    }
  }
  #pragma unroll
  for (int m = 0; m < 4; m++)
    #pragma unroll
    for (int nt = 0; nt < 2; nt++)
      #pragma unroll
      for (int r = 0; r < 4; r++) {
        int i = 16 * m + 4 * g + r, d = 32 * w + 16 * nt + l15;
        float val = 0.5f * o[m][nt][r] + 0.5f * olacc[m][nt][r];
        obf[((size_t)(b * SS + c * 64 + i)) * HIDN + hq * 128 + d] = f2bf(val);
      }
}

// --------------------------------------------------------------------------
extern "C" void kernel_launch(void* const* d_in, const int* in_sizes, int n_in,
                              void* d_out, int out_size, void* d_ws, size_t ws_size,
                              hipStream_t stream)
{
  const float* hs = (const float*)d_in[0];
  const int*  pos = (const int*)d_in[1];
  const float* Wq = (const float*)d_in[2];
  const float* bq = (const float*)d_in[3];
  const float* Wk = (const float*)d_in[4];
  const float* bk = (const float*)d_in[5];
  const float* Wv = (const float*)d_in[6];
  const float* bv = (const float*)d_in[7];
  const float* Wo = (const float*)d_in[8];
  float* out = (float*)d_out;

  float* w = (float*)d_ws;
  const size_t QSZ = (size_t)BB * HH * SS * DD;         // 8388608
  const size_t KSZ = (size_t)BB * HKVV * SS * DD;       // 2097152
  const size_t TSZ = (size_t)BB * HKVV * NCH * DD * DD; // 4194304
  short* hs_bf = (short*)w; w += QSZ / 2;
  float* qbuf  = w; w += QSZ;
  float* kbuf  = w; w += KSZ;
  short* qsm   = (short*)w; w += QSZ / 2;
  short* sqb   = (short*)w; w += QSZ / 2;
  short* ksm   = (short*)w; w += KSZ / 2;
  short* skb   = (short*)w; w += KSZ / 2;
  short* vb    = (short*)w; w += KSZ / 2;
  float* gbuf  = w; w += KSZ;
  float* Gc    = w; w += KSZ;
  float* Tc    = w; w += TSZ;             // bf16 TcB in front half; obf aliases after passB
  short* hT    = (short*)w; w += TSZ / 2;
  float* ct    = w; w += (size_t)SS * 64;
  float* st    = w; w += (size_t)SS * 64;
  short* wo_bf = (short*)w; w += (size_t)HIDN * HIDN / 2;
  short* wqkv_bf = (short*)w; w += (size_t)3072 * HIDN / 2;

  short* TcB = (short*)Tc;   // TSZ bf16 elems = front half of Tc region
  short* obf = (short*)Tc;   // written by gla_win after TcB is dead

  dim3 blk(256);
  const int M = BB * SS; // 4096

  cast_all_k<<<dim3(18944), blk, 0, stream>>>(hs, Wq, Wk, Wv, Wo, pos,
                                              hs_bf, wqkv_bf, wo_bf, ct, st);

  qkv_gemm_k<<<dim3(768), blk, 0, stream>>>(hs_bf, wqkv_bf, bq, bk, bv,
                                            qbuf, kbuf, vb);

  prep_k<<<dim3((BB * HH * SS + BB * HKVV * SS) / 8), blk, 0, stream>>>(
      qbuf, kbuf, ct, st, qsm, sqb, ksm, skb, gbuf);

  gla_passA_k<<<dim3(BB * HKVV * NCH), blk, 0, stream>>>(ksm, vb, gbuf, Gc, TcB);
  gla_passB_k<<<dim3(BB * HKVV * DD * DD / 256), blk, 0, stream>>>(TcB, Gc, hT);

  // fused passC + window attention (olin stays in registers)
  gla_win_k<<<dim3(BB * HH * NCH), blk, 0, stream>>>(qsm, ksm, sqb, skb, vb, Gc, hT, obf);

  mfma_gemm_bt<<<dim3(512), blk, 0, stream>>>(obf, wo_bf, out, M, HIDN, HIDN, 16, 64);
}

// Round 13
// 223.131 us; speedup vs baseline: 1.1833x; 1.0080x over previous
//
#include <hip/hip_runtime.h>
#include <hip/hip_bf16.h>
#include <math.h>

#define BB   2
#define SS   2048
#define HIDN 2048
#define HH   16
#define HKVV 4
#define DD   128
#define NCH  32   // S/CHUNK
#define CHK  64
#define NBLK 32   // S/WIN

typedef __attribute__((ext_vector_type(8))) short bf16x8;
typedef __attribute__((ext_vector_type(4))) float f32x4;

__device__ __forceinline__ short f2bf(float x)
{
  __hip_bfloat16 h = __float2bfloat16(x);
  return *(short*)&h;
}
__device__ __forceinline__ float bf2f(short x)
{
  return __uint_as_float(((uint)(ushort)x) << 16);
}

__device__ __forceinline__ void gld_lds16(const short* g, short* lds)
{
  __builtin_amdgcn_global_load_lds(
      (const __attribute__((address_space(1))) void*)g,
      (__attribute__((address_space(3))) void*)lds, 16, 0, 0);
}

// swizzled LDS helpers: byte ^= ((row&7)<<4) within each 8-row stripe
__device__ __forceinline__ bf16x8 ldsA(const short* base, int row, int rs, int ks)
{
  int byte = (row * rs + ks) * 2;
  byte ^= ((row & 7) << 4);
  __builtin_assume((byte & 15) == 0);
  return *(const bf16x8*)((const char*)base + byte);
}
__device__ __forceinline__ void lds_w16_swz(short* base, int row, int rs, int ks, short v)
{
  int byte = (row * rs + ks) * 2;
  byte ^= ((row & 7) << 4);
  *(short*)((char*)base + byte) = v;
}

// ---------------- combined fp32->bf16 cast + rope table -------------------
__global__ __launch_bounds__(256) void cast_all_k(
    const float* __restrict__ hs, const float* __restrict__ wq,
    const float* __restrict__ wk, const float* __restrict__ wv,
    const float* __restrict__ wo, const int* __restrict__ pos,
    short* __restrict__ hs_bf, short* __restrict__ wqkv_bf, short* __restrict__ wo_bf,
    float* __restrict__ ct, float* __restrict__ st)
{
  int i = blockIdx.x * 256 + threadIdx.x;   // f4 index, total 4718592 + rope 131072
  if (i >= 4718592) {
    int id = i - 4718592;                    // SS*64 entries
    int s = id >> 6, fi = id & 63;
    double inv = pow(1.0e6, -(double)(2 * fi) / 128.0);
    double ang = (double)pos[s] * inv;
    ct[id] = (float)cos(ang);
    st[id] = (float)sin(ang);
    return;
  }
  const float* src; short* dst; int off;
  if (i < 2097152)       { src = hs; dst = hs_bf;            off = i; }
  else if (i < 3145728)  { src = wq; dst = wqkv_bf;          off = i - 2097152; }
  else if (i < 3407872)  { src = wk; dst = wqkv_bf + 4194304; off = i - 3145728; }
  else if (i < 3670016)  { src = wv; dst = wqkv_bf + 5242880; off = i - 3407872; }
  else                   { src = wo; dst = wo_bf;            off = i - 3670016; }
  const float4 v = ((const float4*)src)[off];
  short4 o;
  o.x = f2bf(v.x); o.y = f2bf(v.y); o.z = f2bf(v.z); o.w = f2bf(v.w);
  ((short4*)dst)[off] = o;
}

__device__ __forceinline__ float logsigf(float x)
{
  return (x >= 0.f) ? -log1pf(expf(-x)) : x - log1pf(expf(x));
}

// ---------------- fused QKV GEMM: minimal epilogue (r4/r9-proven) ---------
// XCD-region mapping: 8 regions of 8M x 12N tiles (squarer L2 footprint).
__global__ __launch_bounds__(256) void qkv_gemm_k(
    const short* __restrict__ A, const short* __restrict__ Bt,
    const float* __restrict__ bq, const float* __restrict__ bk,
    const float* __restrict__ bv,
    float* __restrict__ qbuf, float* __restrict__ kbuf, short* __restrict__ vb)
{
  const int K = HIDN;
  __shared__ short As[128 * 32];
  __shared__ short Bs[128 * 32];
  int orig = blockIdx.x;
  int x = orig & 7, t = orig >> 3;         // 96 wg per XCD
  int rx = x >> 1, cx = x & 1;             // 4x2 regions of 8M x 12N
  int bm = (rx * 8 + t / 12) * 128;
  int bn = (cx * 12 + t % 12) * 128;
  int tid = threadIdx.x;
  int wave = tid >> 6, lane = tid & 63;
  int wr = wave >> 1, wc = wave & 1;
  int l15 = lane & 15, g4i = lane >> 4;

  f32x4 acc[4][4];
  #pragma unroll
  for (int m = 0; m < 4; m++)
    #pragma unroll
    for (int n = 0; n < 4; n++) acc[m][n] = (f32x4){0.f, 0.f, 0.f, 0.f};

  int srow = lane >> 2;
  int scol = (lane & 3) * 8;
  const short* Abase = A + (size_t)bm * K;
  const short* Bbase = Bt + (size_t)bn * K;

  for (int k0 = 0; k0 < K; k0 += 32) {
    #pragma unroll
    for (int tt = wave; tt < 8; tt += 4) {
      gld_lds16(Abase + (size_t)(tt * 16 + srow) * K + k0 + scol, &As[tt * 512]);
      gld_lds16(Bbase + (size_t)(tt * 16 + srow) * K + k0 + scol, &Bs[tt * 512]);
    }
    __syncthreads();
    int koff = g4i * 8;
    int ar = wr * 64 + l15;
    int br = wc * 64 + l15;
    bf16x8 af[4], bfr[4];
    #pragma unroll
    for (int m = 0; m < 4; m++) af[m] = *(const bf16x8*)&As[(ar + m * 16) * 32 + koff];
    #pragma unroll
    for (int n = 0; n < 4; n++) bfr[n] = *(const bf16x8*)&Bs[(br + n * 16) * 32 + koff];
    #pragma unroll
    for (int m = 0; m < 4; m++)
      #pragma unroll
      for (int n = 0; n < 4; n++)
        acc[m][n] = __builtin_amdgcn_mfma_f32_16x16x32_bf16(af[m], bfr[n], acc[m][n], 0, 0, 0);
    __syncthreads();
  }

  int proj = (bn < 2048) ? 0 : ((bn < 2560) ? 1 : 2);
  int nbase = (proj == 0) ? bn : ((proj == 1) ? bn - 2048 : bn - 2560);
  const float* bias = (proj == 0) ? bq : ((proj == 1) ? bk : bv);
  float* fdst = (proj == 0) ? qbuf : kbuf;
  int NHp = (proj == 0) ? HH : HKVV;

  int crow0 = wr * 64 + g4i * 4;
  int ccol0 = wc * 64 + l15;
  #pragma unroll
  for (int m = 0; m < 4; m++) {
    #pragma unroll
    for (int n = 0; n < 4; n++) {
      int nn = nbase + ccol0 + n * 16;
      float bvl = bias[nn];
      int hh = nn >> 7, d = nn & 127;
      #pragma unroll
      for (int r = 0; r < 4; r++) {
        int mm = bm + crow0 + m * 16 + r;
        int b = mm >> 11, s = mm & 2047;
        float val = acc[m][n][r] + bvl;
        size_t idx = (size_t)((b * NHp + hh) * SS + s) * DD + d;
        if (proj == 2) vb[idx] = f2bf(val);
        else fdst[idx] = val;
      }
    }
  }
}

// ---------------- prep: softmax + rope (+gate for k) from f32 q/k ---------
__global__ __launch_bounds__(256) void prep_k(
    const float* __restrict__ qbuf, const float* __restrict__ kbuf,
    const float* __restrict__ ct, const float* __restrict__ st,
    short* __restrict__ qsm, short* __restrict__ sqb,
    short* __restrict__ ksm, short* __restrict__ skb, float* __restrict__ gbuf)
{
  int rowid = blockIdx.x * 8 + (threadIdx.x >> 5);
  int l32 = threadIdx.x & 31;
  bool isq = rowid < (BB * HH * SS);
  int row = isq ? rowid : rowid - BB * HH * SS;
  int s = row & (SS - 1);
  size_t base = (size_t)row * 128;
  int c = l32 * 4;
  const float* src = isq ? qbuf : kbuf;
  float4 x4 = *(const float4*)(src + base + c);
  float x0 = x4.x, x1 = x4.y, x2 = x4.z, x3 = x4.w;

  float p0 = __shfl_xor(x0, 16), p1 = __shfl_xor(x1, 16);
  float p2 = __shfl_xor(x2, 16), p3 = __shfl_xor(x3, 16);
  int f = c & 63;
  float4 cv = *(const float4*)(ct + (size_t)s * 64 + f);
  float4 sv = *(const float4*)(st + (size_t)s * 64 + f);
  float sgn = (c < 64) ? -1.f : 1.f;
  short4 r4;
  r4.x = f2bf(x0 * cv.x + sgn * p0 * sv.x);
  r4.y = f2bf(x1 * cv.y + sgn * p1 * sv.y);
  r4.z = f2bf(x2 * cv.z + sgn * p2 * sv.z);
  r4.w = f2bf(x3 * cv.w + sgn * p3 * sv.w);
  *(short4*)((isq ? sqb : skb) + base + c) = r4;

  if (!isq) {
    float4 gv = make_float4(logsigf(x0) * (1.0f / 16.0f), logsigf(x1) * (1.0f / 16.0f),
                            logsigf(x2) * (1.0f / 16.0f), logsigf(x3) * (1.0f / 16.0f));
    *(float4*)(gbuf + base + c) = gv;
  }

  float m = fmaxf(fmaxf(x0, x1), fmaxf(x2, x3));
  #pragma unroll
  for (int msk = 1; msk < 32; msk <<= 1) m = fmaxf(m, __shfl_xor(m, msk));
  float e0 = __expf(x0 - m), e1 = __expf(x1 - m), e2 = __expf(x2 - m), e3 = __expf(x3 - m);
  float sum = e0 + e1 + e2 + e3;
  #pragma unroll
  for (int msk = 1; msk < 32; msk <<= 1) sum += __shfl_xor(sum, msk);
  float inv = 1.0f / sum;
  short4 o;
  o.x = f2bf(e0 * inv); o.y = f2bf(e1 * inv); o.z = f2bf(e2 * inv); o.w = f2bf(e3 * inv);
  *(short4*)((isq ? qsm : ksm) + base + c) = o;
}

// ---------------- bf16 MFMA GEMM (Wo): 8 regions of 8M x 8N tiles ---------
__global__ __launch_bounds__(256) void mfma_gemm_bt(
    const short* __restrict__ A, const short* __restrict__ Bt,
    float* __restrict__ C, int M, int N, int K)
{
  __shared__ short As[128 * 32];
  __shared__ short Bs[128 * 32];
  int orig = blockIdx.x;
  int x = orig & 7, t = orig >> 3;         // 64 wg per XCD
  int rx = x >> 1, cx = x & 1;             // 4x2 regions of 8M x 8N
  int bm = (rx * 8 + t / 8) * 128;
  int bn = (cx * 8 + t % 8) * 128;
  int tid = threadIdx.x;
  int wave = tid >> 6, lane = tid & 63;
  int wr = wave >> 1, wc = wave & 1;

  f32x4 acc[4][4];
  #pragma unroll
  for (int m = 0; m < 4; m++)
    #pragma unroll
    for (int n = 0; n < 4; n++) acc[m][n] = (f32x4){0.f, 0.f, 0.f, 0.f};

  int srow = lane >> 2;
  int scol = (lane & 3) * 8;
  const short* Abase = A + (size_t)bm * K;
  const short* Bbase = Bt + (size_t)bn * K;

  for (int k0 = 0; k0 < K; k0 += 32) {
    #pragma unroll
    for (int tt = wave; tt < 8; tt += 4) {
      gld_lds16(Abase + (size_t)(tt * 16 + srow) * K + k0 + scol, &As[tt * 512]);
      gld_lds16(Bbase + (size_t)(tt * 16 + srow) * K + k0 + scol, &Bs[tt * 512]);
    }
    __syncthreads();
    int koff = (lane >> 4) * 8;
    int ar = wr * 64 + (lane & 15);
    int br = wc * 64 + (lane & 15);
    bf16x8 af[4], bfr[4];
    #pragma unroll
    for (int m = 0; m < 4; m++) af[m] = *(const bf16x8*)&As[(ar + m * 16) * 32 + koff];
    #pragma unroll
    for (int n = 0; n < 4; n++) bfr[n] = *(const bf16x8*)&Bs[(br + n * 16) * 32 + koff];
    #pragma unroll
    for (int m = 0; m < 4; m++)
      #pragma unroll
      for (int n = 0; n < 4; n++)
        acc[m][n] = __builtin_amdgcn_mfma_f32_16x16x32_bf16(af[m], bfr[n], acc[m][n], 0, 0, 0);
    __syncthreads();
  }

  int crow0 = wr * 64 + (lane >> 4) * 4;
  int ccol0 = wc * 64 + (lane & 15);
  #pragma unroll
  for (int m = 0; m < 4; m++)
    #pragma unroll
    for (int n = 0; n < 4; n++) {
      int nn = bn + ccol0 + n * 16;
      #pragma unroll
      for (int r = 0; r < 4; r++) {
        int mm = bm + crow0 + m * 16 + r;
        C[(size_t)mm * N + nn] = acc[m][n][r];
      }
    }
}

// ---------------- GLA pass A (MFMA): Gc cumsum + Tc bf16 as [v][k] --------
__global__ __launch_bounds__(256) void gla_passA_k(
    const short* __restrict__ ksb, const short* __restrict__ vbb,
    const float* __restrict__ g, float* __restrict__ Gc, short* __restrict__ TcB)
{
  int bx = blockIdx.x;             // bkvh*NCH + c
  int c = bx & 31;
  int bkvh = bx >> 5;
  __shared__ float Gs[64][128];
  __shared__ short KgT[128 * 64];
  __shared__ short VT[128 * 64];
  size_t rowbase = ((size_t)bkvh * SS + c * 64) * 128;
  int tid = threadIdx.x, w = tid >> 6, l = tid & 63, gi = l >> 4;

  {
    int j = tid >> 2, d0 = (tid & 3) * 32;
    const float4* g4 = (const float4*)(g + rowbase + j * 128 + d0);
    float4* gs4 = (float4*)&Gs[j][d0];
    #pragma unroll
    for (int u = 0; u < 8; u++) gs4[u] = g4[u];
  }
  __syncthreads();
  if (tid < 128) {
    float run = 0.f;
    for (int j = 0; j < 64; j++) { run += Gs[j][tid]; Gs[j][tid] = run; }
  }
  __syncthreads();
  {
    int j = tid >> 2, d0 = (tid & 3) * 32;
    float4* gc4 = (float4*)(Gc + rowbase + j * 128 + d0);
    const float4* gs4 = (const float4*)&Gs[j][d0];
    #pragma unroll
    for (int u = 0; u < 8; u++) gc4[u] = gs4[u];
  }
  {
    int j = tid >> 2, d0 = (tid & 3) * 32;
    const bf16x8* k8 = (const bf16x8*)(ksb + rowbase + j * 128 + d0);
    const bf16x8* v8 = (const bf16x8*)(vbb + rowbase + j * 128 + d0);
    #pragma unroll
    for (int u = 0; u < 4; u++) {
      bf16x8 kv = k8[u], vv = v8[u];
      #pragma unroll
      for (int e = 0; e < 8; e++) {
        int d = d0 + u * 8 + e;
        float kg = bf2f(kv[e]) * __expf(Gs[63][d] - Gs[j][d]);
        lds_w16_swz(KgT, d, 64, j, f2bf(kg));
        lds_w16_swz(VT, d, 64, j, vv[e]);
      }
    }
  }
  __syncthreads();
  f32x4 acc[2][8];
  #pragma unroll
  for (int m = 0; m < 2; m++)
    #pragma unroll
    for (int n = 0; n < 8; n++) acc[m][n] = (f32x4){0.f, 0.f, 0.f, 0.f};
  #pragma unroll
  for (int k0i = 0; k0i < 2; k0i++) {
    int k0 = k0i * 32 + gi * 8;
    bf16x8 af[2];
    #pragma unroll
    for (int m = 0; m < 2; m++) af[m] = ldsA(VT, 32 * w + 16 * m + (l & 15), 64, k0);
    #pragma unroll
    for (int n = 0; n < 8; n++) {
      bf16x8 bfr = ldsA(KgT, 16 * n + (l & 15), 64, k0);
      #pragma unroll
      for (int m = 0; m < 2; m++)
        acc[m][n] = __builtin_amdgcn_mfma_f32_16x16x32_bf16(af[m], bfr, acc[m][n], 0, 0, 0);
    }
  }
  size_t tbase = (size_t)bx * 16384;
  #pragma unroll
  for (int m = 0; m < 2; m++)
    #pragma unroll
    for (int n = 0; n < 8; n++)
      #pragma unroll
      for (int r = 0; r < 4; r++) {
        int vv = 32 * w + 16 * m + 4 * gi + r;
        int kk = 16 * n + (l & 15);
        TcB[tbase + (size_t)vv * 128 + kk] = f2bf(acc[m][n][r]);
      }
}

// ---------------- GLA pass B: scan; TcB bf16 [v][k]; writes hT bf16 -------
__global__ __launch_bounds__(256) void gla_passB_k(
    const short* __restrict__ TcB, const float* __restrict__ Gc,
    short* __restrict__ hT)
{
  int id = blockIdx.x * 256 + threadIdx.x; // (bkvh, v, k)
  int bkvh = id >> 14;
  int vk = id & 16383;
  int kk = vk & 127;
  float h = 0.f;
  for (int c = 0; c < NCH; ++c) {
    size_t cb = ((size_t)(bkvh * NCH + c) << 14);
    hT[cb + vk] = f2bf(h);
    float gl = Gc[((size_t)bkvh * SS + c * 64 + 63) * 128 + kk];
    h = h * __expf(gl) + bf2f(TcB[cb + vk]);
  }
}

// ---------------- FUSED GLA pass C + windowed attention -------------------
__global__ __launch_bounds__(256) void gla_win_k(
    const short* __restrict__ qsm, const short* __restrict__ ksm,
    const short* __restrict__ sqb, const short* __restrict__ skb,
    const short* __restrict__ vbb, const float* __restrict__ Gc,
    const short* __restrict__ hT, short* __restrict__ obf)
{
  int bx = blockIdx.x;            // (b*H+h)*NCH + c   (c == window block n)
  int c = bx & 31;
  int bh = bx >> 5;
  int b = bh >> 4, hq = bh & 15;
  int bkvh = b * HKVV + (hq >> 2);
  __shared__ short SA[64 * 128];   // QeB -> Qs -> P
  __shared__ short SB[64 * 128];   // KeB/AmB -> Ks rows 0-63 -> V^T rows 0-63
  __shared__ short SC[128 * 64];   // VtB -> Ks rows 64-127 -> V^T rows 64-127
  __shared__ float wred[2][4][64];
  int tid = threadIdx.x, w = tid >> 6, l = tid & 63, g = l >> 4;
  int l15 = l & 15;
  size_t qrow = ((size_t)bh * SS + c * 64) * 128;
  size_t krow = ((size_t)bkvh * SS + c * 64) * 128;

  const short* hTb = hT + (((size_t)(bkvh * NCH + c)) << 14);
  bf16x8 hB[4][2];
  #pragma unroll
  for (int k0i = 0; k0i < 4; k0i++)
    #pragma unroll
    for (int nt = 0; nt < 2; nt++)
      hB[k0i][nt] = *(const bf16x8*)(hTb + (size_t)(32 * w + 16 * nt + l15) * 128 + k0i * 32 + g * 8);

  // ---- phase 1 staging: Qe, Ke, V^T ----
  {
    int j = tid >> 2, d0 = (tid & 3) * 32;
    const bf16x8* q8 = (const bf16x8*)(qsm + qrow + (size_t)j * 128 + d0);
    const bf16x8* k8 = (const bf16x8*)(ksm + krow + (size_t)j * 128 + d0);
    const bf16x8* v8 = (const bf16x8*)(vbb + krow + (size_t)j * 128 + d0);
    const float* gp = Gc + krow + (size_t)j * 128 + d0;
    float gcv[32];
    #pragma unroll
    for (int u = 0; u < 8; u++) {
      float4 t = ((const float4*)gp)[u];
      gcv[4 * u] = t.x; gcv[4 * u + 1] = t.y; gcv[4 * u + 2] = t.z; gcv[4 * u + 3] = t.w;
    }
    #pragma unroll
    for (int u = 0; u < 4; u++) {
      bf16x8 qv = q8[u], kv = k8[u], vv = v8[u];
      #pragma unroll
      for (int e = 0; e < 8; e++) {
        int idx = u * 8 + e, d = d0 + idx;
        float eg = __expf(gcv[idx]);
        lds_w16_swz(SA, j, 128, d, f2bf(bf2f(qv[e]) * eg));
        lds_w16_swz(SB, j, 128, d, f2bf(bf2f(kv[e]) / eg));
        lds_w16_swz(SC, d, 64, j, vv[e]);
      }
    }
  }
  __syncthreads(); // B0

  f32x4 acc1[4];
  #pragma unroll
  for (int m = 0; m < 4; m++) acc1[m] = (f32x4){0.f, 0.f, 0.f, 0.f};
  #pragma unroll
  for (int k0i = 0; k0i < 4; k0i++) {
    int k0 = k0i * 32 + g * 8;
    bf16x8 bk = ldsA(SB, 16 * w + l15, 128, k0);
    #pragma unroll
    for (int m = 0; m < 4; m++) {
      bf16x8 af = ldsA(SA, 16 * m + l15, 128, k0);
      acc1[m] = __builtin_amdgcn_mfma_f32_16x16x32_bf16(af, bk, acc1[m], 0, 0, 0);
    }
  }
  __syncthreads(); // B1
  #pragma unroll
  for (int m = 0; m < 4; m++)
    #pragma unroll
    for (int r = 0; r < 4; r++) {
      int i = 16 * m + 4 * g + r;
      int j = 16 * w + l15;
      float val = (j <= i) ? acc1[m][r] : 0.f;
      lds_w16_swz(SB, i, 64, j, f2bf(val));   // AmB over KeB
    }
  __syncthreads(); // B2

  f32x4 olacc[4][2];
  #pragma unroll
  for (int m = 0; m < 4; m++)
    #pragma unroll
    for (int nt = 0; nt < 2; nt++) olacc[m][nt] = (f32x4){0.f, 0.f, 0.f, 0.f};
  #pragma unroll
  for (int k0i = 0; k0i < 2; k0i++) {
    int k0 = k0i * 32 + g * 8;
    bf16x8 bfr[2];
    #pragma unroll
    for (int nt = 0; nt < 2; nt++) bfr[nt] = ldsA(SC, 32 * w + 16 * nt + l15, 64, k0);
    #pragma unroll
    for (int m = 0; m < 4; m++) {
      bf16x8 af = ldsA(SB, 16 * m + l15, 64, k0);
      #pragma unroll
      for (int nt = 0; nt < 2; nt++)
        olacc[m][nt] = __builtin_amdgcn_mfma_f32_16x16x32_bf16(af, bfr[nt], olacc[m][nt], 0, 0, 0);
    }
  }
  #pragma unroll
  for (int k0i = 0; k0i < 4; k0i++) {
    int k0 = k0i * 32 + g * 8;
    #pragma unroll
    for (int m = 0; m < 4; m++) {
      bf16x8 af = ldsA(SA, 16 * m + l15, 128, k0);
      #pragma unroll
      for (int nt = 0; nt < 2; nt++)
        olacc[m][nt] = __builtin_amdgcn_mfma_f32_16x16x32_bf16(af, hB[k0i][nt], olacc[m][nt], 0, 0, 0);
    }
  }
  __syncthreads(); // B3

  // ---- phase 2 staging: roped Q -> SA, roped K window -> SB/SC ----
  {
    const short* qg = sqb + qrow;
    const short* kg = skb + (size_t)bkvh * SS * 128 + (ptrdiff_t)(c - 1) * 64 * 128;
    for (int c0 = w * 64; c0 < 1024; c0 += 256) {
      int cc = c0 + l, row = cc >> 4;
      int gb = (cc << 4) ^ ((row & 7) << 4);
      gld_lds16((const short*)((const char*)qg + gb), SA + c0 * 8);
    }
    for (int c0 = w * 64; c0 < 2048; c0 += 256) {
      int cc = c0 + l, row = cc >> 4;
      int gb = (cc << 4) ^ ((row & 7) << 4);
      short* dst = (c0 < 1024) ? (SB + c0 * 8) : (SC + (c0 - 1024) * 8);
      gld_lds16((const short*)((const char*)kg + gb), dst);
    }
  }
  __syncthreads(); // B4

  f32x4 acc[4][2];
  #pragma unroll
  for (int m = 0; m < 4; m++)
    #pragma unroll
    for (int nt = 0; nt < 2; nt++) acc[m][nt] = (f32x4){0.f, 0.f, 0.f, 0.f};
  #pragma unroll
  for (int k0i = 0; k0i < 4; k0i++) {
    int k0 = k0i * 32 + g * 8;
    bf16x8 bfr[2];
    #pragma unroll
    for (int nt = 0; nt < 2; nt++) {
      int row = 32 * w + 16 * nt + l15;
      bfr[nt] = (row < 64) ? ldsA(SB, row, 128, k0) : ldsA(SC, row - 64, 128, k0);
    }
    #pragma unroll
    for (int m = 0; m < 4; m++) {
      bf16x8 af = ldsA(SA, 16 * m + l15, 128, k0);
      #pragma unroll
      for (int nt = 0; nt < 2; nt++)
        acc[m][nt] = __builtin_amdgcn_mfma_f32_16x16x32_bf16(af, bfr[nt], acc[m][nt], 0, 0, 0);
    }
  }

  const float scale = 0.08838834764831845f;
  float mx[4][4];
  #pragma unroll
  for (int m = 0; m < 4; m++)
    #pragma unroll
    for (int r = 0; r < 4; r++) mx[m][r] = -1e30f;
  #pragma unroll
  for (int m = 0; m < 4; m++)
    #pragma unroll
    for (int nt = 0; nt < 2; nt++)
      #pragma unroll
      for (int r = 0; r < 4; r++) {
        int i = 16 * m + 4 * g + r;
        int j = 32 * w + 16 * nt + l15;
        int kp = (c - 1) * 64 + j;
        bool valid = (j >= i) && (j <= i + 64) && (kp >= 0);
        float sc = valid ? acc[m][nt][r] * scale : -1e30f;
        acc[m][nt][r] = sc;
        mx[m][r] = fmaxf(mx[m][r], sc);
      }
  #pragma unroll
  for (int m = 0; m < 4; m++)
    #pragma unroll
    for (int r = 0; r < 4; r++) {
      #pragma unroll
      for (int msk = 1; msk < 16; msk <<= 1) mx[m][r] = fmaxf(mx[m][r], __shfl_xor(mx[m][r], msk));
    }
  if (l15 == 0)
    #pragma unroll
    for (int m = 0; m < 4; m++)
      #pragma unroll
      for (int r = 0; r < 4; r++) wred[0][w][16 * m + 4 * g + r] = mx[m][r];
  __syncthreads(); // B5

  float mrow[4][4], sm[4][4];
  #pragma unroll
  for (int m = 0; m < 4; m++)
    #pragma unroll
    for (int r = 0; r < 4; r++) {
      int i = 16 * m + 4 * g + r;
      mrow[m][r] = fmaxf(fmaxf(wred[0][0][i], wred[0][1][i]), fmaxf(wred[0][2][i], wred[0][3][i]));
      sm[m][r] = 0.f;
    }
  #pragma unroll
  for (int m = 0; m < 4; m++)
    #pragma unroll
    for (int nt = 0; nt < 2; nt++)
      #pragma unroll
      for (int r = 0; r < 4; r++) {
        float p = __expf(acc[m][nt][r] - mrow[m][r]);
        acc[m][nt][r] = p;
        sm[m][r] += p;
      }
  #pragma unroll
  for (int m = 0; m < 4; m++)
    #pragma unroll
    for (int r = 0; r < 4; r++) {
      #pragma unroll
      for (int msk = 1; msk < 16; msk <<= 1) sm[m][r] += __shfl_xor(sm[m][r], msk);
    }
  if (l15 == 0)
    #pragma unroll
    for (int m = 0; m < 4; m++)
      #pragma unroll
      for (int r = 0; r < 4; r++) wred[1][w][16 * m + 4 * g + r] = sm[m][r];
  __syncthreads(); // B6

  #pragma unroll
  for (int m = 0; m < 4; m++)
    #pragma unroll
    for (int r = 0; r < 4; r++) {
      int i = 16 * m + 4 * g + r;
      float s = wred[1][0][i] + wred[1][1][i] + wred[1][2][i] + wred[1][3][i];
      float inv = 1.0f / s;
      #pragma unroll
      for (int nt = 0; nt < 2; nt++) {
        int j = 32 * w + 16 * nt + l15;
        lds_w16_swz(SA, i, 128, j, f2bf(acc[m][nt][r] * inv));
      }
    }
  {
    int j = tid >> 1, dh = (tid & 1) * 64;
    int kp = (c - 1) * 64 + j;
    const short* vrow = vbb + ((size_t)bkvh * SS + kp) * 128 + dh;
    #pragma unroll
    for (int u = 0; u < 8; u++) {
      bf16x8 vv;
      if (kp >= 0) vv = *(const bf16x8*)(vrow + u * 8);
      else vv = (bf16x8){0, 0, 0, 0, 0, 0, 0, 0};
      #pragma unroll
      for (int i2 = 0; i2 < 8; i2++) {
        int row = dh + u * 8 + i2;
        if (row < 64) lds_w16_swz(SB, row, 128, j, vv[i2]);
        else lds_w16_swz(SC, row - 64, 128, j, vv[i2]);
      }
    }
  }
  __syncthreads(); // B7

  f32x4 o[4][2];
  #pragma unroll
  for (int m = 0; m < 4; m++)
    #pragma unroll
    for (int nt = 0; nt < 2; nt++) o[m][nt] = (f32x4){0.f, 0.f, 0.f, 0.f};
  #pragma unroll
  for (int k0i = 0; k0i < 4; k0i++) {
    int k0 = k0i * 32 + g * 8;
    bf16x8 bfr[2];
    #pragma unroll
    for (int nt = 0; nt < 2; nt++) {
      int row = 32 * w + 16 * nt + l15;
      bfr[nt] = (row < 64) ? ldsA(SB, row, 128, k0) : ldsA(SC, row - 64, 128, k0);
    }
    #pragma unroll
    for (int m = 0; m < 4; m++) {
      bf16x8 af = ldsA(SA, 16 * m + l15, 128, k0);
      #pragma unroll
      for (int nt = 0; nt < 2; nt++)
        o[m][nt] = __builtin_amdgcn_mfma_f32_16x16x32_bf16(af, bfr[nt], o[m][nt], 0, 0, 0);
    }
  }
  #pragma unroll
  for (int m = 0; m < 4; m++)
    #pragma unroll
    for (int nt = 0; nt < 2; nt++)
      #pragma unroll
      for (int r = 0; r < 4; r++) {
        int i = 16 * m + 4 * g + r, d = 32 * w + 16 * nt + l15;
        float val = 0.5f * o[m][nt][r] + 0.5f * olacc[m][nt][r];
        obf[((size_t)(b * SS + c * 64 + i)) * HIDN + hq * 128 + d] = f2bf(val);
      }
}

// --------------------------------------------------------------------------
extern "C" void kernel_launch(void* const* d_in, const int* in_sizes, int n_in,
                              void* d_out, int out_size, void* d_ws, size_t ws_size,
                              hipStream_t stream)
{
  const float* hs = (const float*)d_in[0];
  const int*  pos = (const int*)d_in[1];
  const float* Wq = (const float*)d_in[2];
  const float* bq = (const float*)d_in[3];
  const float* Wk = (const float*)d_in[4];
  const float* bk = (const float*)d_in[5];
  const float* Wv = (const float*)d_in[6];
  const float* bv = (const float*)d_in[7];
  const float* Wo = (const float*)d_in[8];
  float* out = (float*)d_out;

  float* w = (float*)d_ws;
  const size_t QSZ = (size_t)BB * HH * SS * DD;         // 8388608
  const size_t KSZ = (size_t)BB * HKVV * SS * DD;       // 2097152
  const size_t TSZ = (size_t)BB * HKVV * NCH * DD * DD; // 4194304
  short* hs_bf = (short*)w; w += QSZ / 2;
  float* qbuf  = w; w += QSZ;
  float* kbuf  = w; w += KSZ;
  short* qsm   = (short*)w; w += QSZ / 2;
  short* sqb   = (short*)w; w += QSZ / 2;
  short* ksm   = (short*)w; w += KSZ / 2;
  short* skb   = (short*)w; w += KSZ / 2;
  short* vb    = (short*)w; w += KSZ / 2;
  float* gbuf  = w; w += KSZ;
  float* Gc    = w; w += KSZ;
  float* Tc    = w; w += TSZ;             // bf16 TcB in front half; obf aliases after passB
  short* hT    = (short*)w; w += TSZ / 2;
  float* ct    = w; w += (size_t)SS * 64;
  float* st    = w; w += (size_t)SS * 64;
  short* wo_bf = (short*)w; w += (size_t)HIDN * HIDN / 2;
  short* wqkv_bf = (short*)w; w += (size_t)3072 * HIDN / 2;

  short* TcB = (short*)Tc;
  short* obf = (short*)Tc;

  dim3 blk(256);
  const int M = BB * SS; // 4096

  cast_all_k<<<dim3(18944), blk, 0, stream>>>(hs, Wq, Wk, Wv, Wo, pos,
                                              hs_bf, wqkv_bf, wo_bf, ct, st);

  qkv_gemm_k<<<dim3(768), blk, 0, stream>>>(hs_bf, wqkv_bf, bq, bk, bv,
                                            qbuf, kbuf, vb);

  prep_k<<<dim3((BB * HH * SS + BB * HKVV * SS) / 8), blk, 0, stream>>>(
      qbuf, kbuf, ct, st, qsm, sqb, ksm, skb, gbuf);

  gla_passA_k<<<dim3(BB * HKVV * NCH), blk, 0, stream>>>(ksm, vb, gbuf, Gc, TcB);
  gla_passB_k<<<dim3(BB * HKVV * DD * DD / 256), blk, 0, stream>>>(TcB, Gc, hT);

  gla_win_k<<<dim3(BB * HH * NCH), blk, 0, stream>>>(qsm, ksm, sqb, skb, vb, Gc, hT, obf);

  mfma_gemm_bt<<<dim3(512), blk, 0, stream>>>(obf, wo_bf, out, M, HIDN, HIDN);
}

// Round 14
// 223.104 us; speedup vs baseline: 1.1835x; 1.0001x over previous
//
#include <hip/hip_runtime.h>
#include <hip/hip_bf16.h>
#include <math.h>

#define BB   2
#define SS   2048
#define HIDN 2048
#define HH   16
#define HKVV 4
#define DD   128
#define NCH  32   // S/CHUNK
#define CHK  64
#define NBLK 32   // S/WIN

typedef __attribute__((ext_vector_type(8))) short bf16x8;
typedef __attribute__((ext_vector_type(4))) float f32x4;

__device__ __forceinline__ short f2bf(float x)
{
  __hip_bfloat16 h = __float2bfloat16(x);
  return *(short*)&h;
}
__device__ __forceinline__ float bf2f(short x)
{
  return __uint_as_float(((uint)(ushort)x) << 16);
}

__device__ __forceinline__ void gld_lds16(const short* g, short* lds)
{
  __builtin_amdgcn_global_load_lds(
      (const __attribute__((address_space(1))) void*)g,
      (__attribute__((address_space(3))) void*)lds, 16, 0, 0);
}

// swizzled LDS helpers: byte ^= ((row&7)<<4) within each 8-row stripe
__device__ __forceinline__ bf16x8 ldsA(const short* base, int row, int rs, int ks)
{
  int byte = (row * rs + ks) * 2;
  byte ^= ((row & 7) << 4);
  __builtin_assume((byte & 15) == 0);
  return *(const bf16x8*)((const char*)base + byte);
}
__device__ __forceinline__ void lds_w16_swz(short* base, int row, int rs, int ks, short v)
{
  int byte = (row * rs + ks) * 2;
  byte ^= ((row & 7) << 4);
  *(short*)((char*)base + byte) = v;
}
__device__ __forceinline__ void lds_w128_swz(short* base, int row, int rs, int ks, bf16x8 v)
{
  int byte = (row * rs + ks) * 2;   // ks multiple of 8 -> 16B aligned; XOR bits >= bit4
  byte ^= ((row & 7) << 4);
  *(bf16x8*)((char*)base + byte) = v;
}

// ---------------- combined fp32->bf16 cast + rope table -------------------
__global__ __launch_bounds__(256) void cast_all_k(
    const float* __restrict__ hs, const float* __restrict__ wq,
    const float* __restrict__ wk, const float* __restrict__ wv,
    const float* __restrict__ wo, const int* __restrict__ pos,
    short* __restrict__ hs_bf, short* __restrict__ wqkv_bf, short* __restrict__ wo_bf,
    float* __restrict__ ct, float* __restrict__ st)
{
  int i = blockIdx.x * 256 + threadIdx.x;   // f4 index, total 4718592 + rope 131072
  if (i >= 4718592) {
    int id = i - 4718592;                    // SS*64 entries
    int s = id >> 6, fi = id & 63;
    double inv = pow(1.0e6, -(double)(2 * fi) / 128.0);
    double ang = (double)pos[s] * inv;
    ct[id] = (float)cos(ang);
    st[id] = (float)sin(ang);
    return;
  }
  const float* src; short* dst; int off;
  if (i < 2097152)       { src = hs; dst = hs_bf;            off = i; }
  else if (i < 3145728)  { src = wq; dst = wqkv_bf;          off = i - 2097152; }
  else if (i < 3407872)  { src = wk; dst = wqkv_bf + 4194304; off = i - 3145728; }
  else if (i < 3670016)  { src = wv; dst = wqkv_bf + 5242880; off = i - 3407872; }
  else                   { src = wo; dst = wo_bf;            off = i - 3670016; }
  const float4 v = ((const float4*)src)[off];
  short4 o;
  o.x = f2bf(v.x); o.y = f2bf(v.y); o.z = f2bf(v.z); o.w = f2bf(v.w);
  ((short4*)dst)[off] = o;
}

__device__ __forceinline__ float logsigf(float x)
{
  return (x >= 0.f) ? -log1pf(expf(-x)) : x - log1pf(expf(x));
}

// ---------------- fused QKV GEMM: minimal epilogue (r4/r9-proven) ---------
// XCD-region mapping: 8 regions of 8M x 12N tiles (squarer L2 footprint).
__global__ __launch_bounds__(256) void qkv_gemm_k(
    const short* __restrict__ A, const short* __restrict__ Bt,
    const float* __restrict__ bq, const float* __restrict__ bk,
    const float* __restrict__ bv,
    float* __restrict__ qbuf, float* __restrict__ kbuf, short* __restrict__ vb)
{
  const int K = HIDN;
  __shared__ short As[128 * 32];
  __shared__ short Bs[128 * 32];
  int orig = blockIdx.x;
  int x = orig & 7, t = orig >> 3;         // 96 wg per XCD
  int rx = x >> 1, cx = x & 1;             // 4x2 regions of 8M x 12N
  int bm = (rx * 8 + t / 12) * 128;
  int bn = (cx * 12 + t % 12) * 128;
  int tid = threadIdx.x;
  int wave = tid >> 6, lane = tid & 63;
  int wr = wave >> 1, wc = wave & 1;
  int l15 = lane & 15, g4i = lane >> 4;

  f32x4 acc[4][4];
  #pragma unroll
  for (int m = 0; m < 4; m++)
    #pragma unroll
    for (int n = 0; n < 4; n++) acc[m][n] = (f32x4){0.f, 0.f, 0.f, 0.f};

  int srow = lane >> 2;
  int scol = (lane & 3) * 8;
  const short* Abase = A + (size_t)bm * K;
  const short* Bbase = Bt + (size_t)bn * K;

  for (int k0 = 0; k0 < K; k0 += 32) {
    #pragma unroll
    for (int tt = wave; tt < 8; tt += 4) {
      gld_lds16(Abase + (size_t)(tt * 16 + srow) * K + k0 + scol, &As[tt * 512]);
      gld_lds16(Bbase + (size_t)(tt * 16 + srow) * K + k0 + scol, &Bs[tt * 512]);
    }
    __syncthreads();
    int koff = g4i * 8;
    int ar = wr * 64 + l15;
    int br = wc * 64 + l15;
    bf16x8 af[4], bfr[4];
    #pragma unroll
    for (int m = 0; m < 4; m++) af[m] = *(const bf16x8*)&As[(ar + m * 16) * 32 + koff];
    #pragma unroll
    for (int n = 0; n < 4; n++) bfr[n] = *(const bf16x8*)&Bs[(br + n * 16) * 32 + koff];
    #pragma unroll
    for (int m = 0; m < 4; m++)
      #pragma unroll
      for (int n = 0; n < 4; n++)
        acc[m][n] = __builtin_amdgcn_mfma_f32_16x16x32_bf16(af[m], bfr[n], acc[m][n], 0, 0, 0);
    __syncthreads();
  }

  int proj = (bn < 2048) ? 0 : ((bn < 2560) ? 1 : 2);
  int nbase = (proj == 0) ? bn : ((proj == 1) ? bn - 2048 : bn - 2560);
  const float* bias = (proj == 0) ? bq : ((proj == 1) ? bk : bv);
  float* fdst = (proj == 0) ? qbuf : kbuf;
  int NHp = (proj == 0) ? HH : HKVV;

  int crow0 = wr * 64 + g4i * 4;
  int ccol0 = wc * 64 + l15;
  #pragma unroll
  for (int m = 0; m < 4; m++) {
    #pragma unroll
    for (int n = 0; n < 4; n++) {
      int nn = nbase + ccol0 + n * 16;
      float bvl = bias[nn];
      int hh = nn >> 7, d = nn & 127;
      #pragma unroll
      for (int r = 0; r < 4; r++) {
        int mm = bm + crow0 + m * 16 + r;
        int b = mm >> 11, s = mm & 2047;
        float val = acc[m][n][r] + bvl;
        size_t idx = (size_t)((b * NHp + hh) * SS + s) * DD + d;
        if (proj == 2) vb[idx] = f2bf(val);
        else fdst[idx] = val;
      }
    }
  }
}

// ---------------- prep: softmax + rope (+gate for k) from f32 q/k ---------
__global__ __launch_bounds__(256) void prep_k(
    const float* __restrict__ qbuf, const float* __restrict__ kbuf,
    const float* __restrict__ ct, const float* __restrict__ st,
    short* __restrict__ qsm, short* __restrict__ sqb,
    short* __restrict__ ksm, short* __restrict__ skb, float* __restrict__ gbuf)
{
  int rowid = blockIdx.x * 8 + (threadIdx.x >> 5);
  int l32 = threadIdx.x & 31;
  bool isq = rowid < (BB * HH * SS);
  int row = isq ? rowid : rowid - BB * HH * SS;
  int s = row & (SS - 1);
  size_t base = (size_t)row * 128;
  int c = l32 * 4;
  const float* src = isq ? qbuf : kbuf;
  float4 x4 = *(const float4*)(src + base + c);
  float x0 = x4.x, x1 = x4.y, x2 = x4.z, x3 = x4.w;

  float p0 = __shfl_xor(x0, 16), p1 = __shfl_xor(x1, 16);
  float p2 = __shfl_xor(x2, 16), p3 = __shfl_xor(x3, 16);
  int f = c & 63;
  float4 cv = *(const float4*)(ct + (size_t)s * 64 + f);
  float4 sv = *(const float4*)(st + (size_t)s * 64 + f);
  float sgn = (c < 64) ? -1.f : 1.f;
  short4 r4;
  r4.x = f2bf(x0 * cv.x + sgn * p0 * sv.x);
  r4.y = f2bf(x1 * cv.y + sgn * p1 * sv.y);
  r4.z = f2bf(x2 * cv.z + sgn * p2 * sv.z);
  r4.w = f2bf(x3 * cv.w + sgn * p3 * sv.w);
  *(short4*)((isq ? sqb : skb) + base + c) = r4;

  if (!isq) {
    float4 gv = make_float4(logsigf(x0) * (1.0f / 16.0f), logsigf(x1) * (1.0f / 16.0f),
                            logsigf(x2) * (1.0f / 16.0f), logsigf(x3) * (1.0f / 16.0f));
    *(float4*)(gbuf + base + c) = gv;
  }

  float m = fmaxf(fmaxf(x0, x1), fmaxf(x2, x3));
  #pragma unroll
  for (int msk = 1; msk < 32; msk <<= 1) m = fmaxf(m, __shfl_xor(m, msk));
  float e0 = __expf(x0 - m), e1 = __expf(x1 - m), e2 = __expf(x2 - m), e3 = __expf(x3 - m);
  float sum = e0 + e1 + e2 + e3;
  #pragma unroll
  for (int msk = 1; msk < 32; msk <<= 1) sum += __shfl_xor(sum, msk);
  float inv = 1.0f / sum;
  short4 o;
  o.x = f2bf(e0 * inv); o.y = f2bf(e1 * inv); o.z = f2bf(e2 * inv); o.w = f2bf(e3 * inv);
  *(short4*)((isq ? qsm : ksm) + base + c) = o;
}

// ---------------- bf16 MFMA GEMM (Wo): 8 regions of 8M x 8N tiles ---------
__global__ __launch_bounds__(256) void mfma_gemm_bt(
    const short* __restrict__ A, const short* __restrict__ Bt,
    float* __restrict__ C, int M, int N, int K)
{
  __shared__ short As[128 * 32];
  __shared__ short Bs[128 * 32];
  int orig = blockIdx.x;
  int x = orig & 7, t = orig >> 3;         // 64 wg per XCD
  int rx = x >> 1, cx = x & 1;             // 4x2 regions of 8M x 8N
  int bm = (rx * 8 + t / 8) * 128;
  int bn = (cx * 8 + t % 8) * 128;
  int tid = threadIdx.x;
  int wave = tid >> 6, lane = tid & 63;
  int wr = wave >> 1, wc = wave & 1;

  f32x4 acc[4][4];
  #pragma unroll
  for (int m = 0; m < 4; m++)
    #pragma unroll
    for (int n = 0; n < 4; n++) acc[m][n] = (f32x4){0.f, 0.f, 0.f, 0.f};

  int srow = lane >> 2;
  int scol = (lane & 3) * 8;
  const short* Abase = A + (size_t)bm * K;
  const short* Bbase = Bt + (size_t)bn * K;

  for (int k0 = 0; k0 < K; k0 += 32) {
    #pragma unroll
    for (int tt = wave; tt < 8; tt += 4) {
      gld_lds16(Abase + (size_t)(tt * 16 + srow) * K + k0 + scol, &As[tt * 512]);
      gld_lds16(Bbase + (size_t)(tt * 16 + srow) * K + k0 + scol, &Bs[tt * 512]);
    }
    __syncthreads();
    int koff = (lane >> 4) * 8;
    int ar = wr * 64 + (lane & 15);
    int br = wc * 64 + (lane & 15);
    bf16x8 af[4], bfr[4];
    #pragma unroll
    for (int m = 0; m < 4; m++) af[m] = *(const bf16x8*)&As[(ar + m * 16) * 32 + koff];
    #pragma unroll
    for (int n = 0; n < 4; n++) bfr[n] = *(const bf16x8*)&Bs[(br + n * 16) * 32 + koff];
    #pragma unroll
    for (int m = 0; m < 4; m++)
      #pragma unroll
      for (int n = 0; n < 4; n++)
        acc[m][n] = __builtin_amdgcn_mfma_f32_16x16x32_bf16(af[m], bfr[n], acc[m][n], 0, 0, 0);
    __syncthreads();
  }

  int crow0 = wr * 64 + (lane >> 4) * 4;
  int ccol0 = wc * 64 + (lane & 15);
  #pragma unroll
  for (int m = 0; m < 4; m++)
    #pragma unroll
    for (int n = 0; n < 4; n++) {
      int nn = bn + ccol0 + n * 16;
      #pragma unroll
      for (int r = 0; r < 4; r++) {
        int mm = bm + crow0 + m * 16 + r;
        C[(size_t)mm * N + nn] = acc[m][n][r];
      }
    }
}

// ---------------- GLA pass A (MFMA): Gc cumsum + Tc bf16 as [v][k] --------
__global__ __launch_bounds__(256) void gla_passA_k(
    const short* __restrict__ ksb, const short* __restrict__ vbb,
    const float* __restrict__ g, float* __restrict__ Gc, short* __restrict__ TcB)
{
  int bx = blockIdx.x;             // bkvh*NCH + c
  int c = bx & 31;
  int bkvh = bx >> 5;
  __shared__ float Gs[64][128];
  __shared__ short KgT[128 * 64];
  __shared__ short VT[128 * 64];
  size_t rowbase = ((size_t)bkvh * SS + c * 64) * 128;
  int tid = threadIdx.x, w = tid >> 6, l = tid & 63, gi = l >> 4;

  {
    int j = tid >> 2, d0 = (tid & 3) * 32;
    const float4* g4 = (const float4*)(g + rowbase + j * 128 + d0);
    float4* gs4 = (float4*)&Gs[j][d0];
    #pragma unroll
    for (int u = 0; u < 8; u++) gs4[u] = g4[u];
  }
  __syncthreads();
  if (tid < 128) {
    float run = 0.f;
    for (int j = 0; j < 64; j++) { run += Gs[j][tid]; Gs[j][tid] = run; }
  }
  __syncthreads();
  {
    int j = tid >> 2, d0 = (tid & 3) * 32;
    float4* gc4 = (float4*)(Gc + rowbase + j * 128 + d0);
    const float4* gs4 = (const float4*)&Gs[j][d0];
    #pragma unroll
    for (int u = 0; u < 8; u++) gc4[u] = gs4[u];
  }
  {
    int j = tid >> 2, d0 = (tid & 3) * 32;
    const bf16x8* k8 = (const bf16x8*)(ksb + rowbase + j * 128 + d0);
    const bf16x8* v8 = (const bf16x8*)(vbb + rowbase + j * 128 + d0);
    #pragma unroll
    for (int u = 0; u < 4; u++) {
      bf16x8 kv = k8[u], vv = v8[u];
      #pragma unroll
      for (int e = 0; e < 8; e++) {
        int d = d0 + u * 8 + e;
        float kg = bf2f(kv[e]) * __expf(Gs[63][d] - Gs[j][d]);
        lds_w16_swz(KgT, d, 64, j, f2bf(kg));
        lds_w16_swz(VT, d, 64, j, vv[e]);
      }
    }
  }
  __syncthreads();
  f32x4 acc[2][8];
  #pragma unroll
  for (int m = 0; m < 2; m++)
    #pragma unroll
    for (int n = 0; n < 8; n++) acc[m][n] = (f32x4){0.f, 0.f, 0.f, 0.f};
  __builtin_amdgcn_s_setprio(1);
  #pragma unroll
  for (int k0i = 0; k0i < 2; k0i++) {
    int k0 = k0i * 32 + gi * 8;
    bf16x8 af[2];
    #pragma unroll
    for (int m = 0; m < 2; m++) af[m] = ldsA(VT, 32 * w + 16 * m + (l & 15), 64, k0);
    #pragma unroll
    for (int n = 0; n < 8; n++) {
      bf16x8 bfr = ldsA(KgT, 16 * n + (l & 15), 64, k0);
      #pragma unroll
      for (int m = 0; m < 2; m++)
        acc[m][n] = __builtin_amdgcn_mfma_f32_16x16x32_bf16(af[m], bfr, acc[m][n], 0, 0, 0);
    }
  }
  __builtin_amdgcn_s_setprio(0);
  size_t tbase = (size_t)bx * 16384;
  #pragma unroll
  for (int m = 0; m < 2; m++)
    #pragma unroll
    for (int n = 0; n < 8; n++)
      #pragma unroll
      for (int r = 0; r < 4; r++) {
        int vv = 32 * w + 16 * m + 4 * gi + r;
        int kk = 16 * n + (l & 15);
        TcB[tbase + (size_t)vv * 128 + kk] = f2bf(acc[m][n][r]);
      }
}

// ---------------- GLA pass B: scan; TcB bf16 [v][k]; writes hT bf16 -------
__global__ __launch_bounds__(256) void gla_passB_k(
    const short* __restrict__ TcB, const float* __restrict__ Gc,
    short* __restrict__ hT)
{
  int id = blockIdx.x * 256 + threadIdx.x; // (bkvh, v, k)
  int bkvh = id >> 14;
  int vk = id & 16383;
  int kk = vk & 127;
  float h = 0.f;
  for (int c = 0; c < NCH; ++c) {
    size_t cb = ((size_t)(bkvh * NCH + c) << 14);
    hT[cb + vk] = f2bf(h);
    float gl = Gc[((size_t)bkvh * SS + c * 64 + 63) * 128 + kk];
    h = h * __expf(gl) + bf2f(TcB[cb + vk]);
  }
}

// ---------------- FUSED GLA pass C + windowed attention -------------------
__global__ __launch_bounds__(256) void gla_win_k(
    const short* __restrict__ qsm, const short* __restrict__ ksm,
    const short* __restrict__ sqb, const short* __restrict__ skb,
    const short* __restrict__ vbb, const float* __restrict__ Gc,
    const short* __restrict__ hT, short* __restrict__ obf)
{
  int bx = blockIdx.x;            // (b*H+h)*NCH + c   (c == window block n)
  int c = bx & 31;
  int bh = bx >> 5;
  int b = bh >> 4, hq = bh & 15;
  int bkvh = b * HKVV + (hq >> 2);
  __shared__ short SA[64 * 128];   // QeB -> Qs -> P
  __shared__ short SB[64 * 128];   // KeB/AmB -> Ks rows 0-63 -> V^T rows 0-63
  __shared__ short SC[128 * 64];   // VtB -> Ks rows 64-127 -> V^T rows 64-127
  __shared__ float wred[2][4][64];
  int tid = threadIdx.x, w = tid >> 6, l = tid & 63, g = l >> 4;
  int l15 = l & 15;
  size_t qrow = ((size_t)bh * SS + c * 64) * 128;
  size_t krow = ((size_t)bkvh * SS + c * 64) * 128;

  const short* hTb = hT + (((size_t)(bkvh * NCH + c)) << 14);
  bf16x8 hB[4][2];
  #pragma unroll
  for (int k0i = 0; k0i < 4; k0i++)
    #pragma unroll
    for (int nt = 0; nt < 2; nt++)
      hB[k0i][nt] = *(const bf16x8*)(hTb + (size_t)(32 * w + 16 * nt + l15) * 128 + k0i * 32 + g * 8);

  // ---- phase 1 staging: Qe, Ke via packed b128 writes; V^T scatter ----
  {
    int j = tid >> 2, d0 = (tid & 3) * 32;
    const bf16x8* q8 = (const bf16x8*)(qsm + qrow + (size_t)j * 128 + d0);
    const bf16x8* k8 = (const bf16x8*)(ksm + krow + (size_t)j * 128 + d0);
    const bf16x8* v8 = (const bf16x8*)(vbb + krow + (size_t)j * 128 + d0);
    const float* gp = Gc + krow + (size_t)j * 128 + d0;
    float gcv[32];
    #pragma unroll
    for (int u = 0; u < 8; u++) {
      float4 t = ((const float4*)gp)[u];
      gcv[4 * u] = t.x; gcv[4 * u + 1] = t.y; gcv[4 * u + 2] = t.z; gcv[4 * u + 3] = t.w;
    }
    #pragma unroll
    for (int u = 0; u < 4; u++) {
      bf16x8 qv = q8[u], kv = k8[u], vv = v8[u];
      bf16x8 qo, ko;
      #pragma unroll
      for (int e = 0; e < 8; e++) {
        int idx = u * 8 + e;
        float eg = __expf(gcv[idx]);
        qo[e] = f2bf(bf2f(qv[e]) * eg);
        ko[e] = f2bf(bf2f(kv[e]) / eg);
        lds_w16_swz(SC, d0 + idx, 64, j, vv[e]);
      }
      lds_w128_swz(SA, j, 128, d0 + 8 * u, qo);
      lds_w128_swz(SB, j, 128, d0 + 8 * u, ko);
    }
  }
  __syncthreads(); // B0

  f32x4 acc1[4];
  #pragma unroll
  for (int m = 0; m < 4; m++) acc1[m] = (f32x4){0.f, 0.f, 0.f, 0.f};
  __builtin_amdgcn_s_setprio(1);
  #pragma unroll
  for (int k0i = 0; k0i < 4; k0i++) {
    int k0 = k0i * 32 + g * 8;
    bf16x8 bk = ldsA(SB, 16 * w + l15, 128, k0);
    #pragma unroll
    for (int m = 0; m < 4; m++) {
      bf16x8 af = ldsA(SA, 16 * m + l15, 128, k0);
      acc1[m] = __builtin_amdgcn_mfma_f32_16x16x32_bf16(af, bk, acc1[m], 0, 0, 0);
    }
  }
  __builtin_amdgcn_s_setprio(0);
  __syncthreads(); // B1
  #pragma unroll
  for (int m = 0; m < 4; m++)
    #pragma unroll
    for (int r = 0; r < 4; r++) {
      int i = 16 * m + 4 * g + r;
      int j = 16 * w + l15;
      float val = (j <= i) ? acc1[m][r] : 0.f;
      lds_w16_swz(SB, i, 64, j, f2bf(val));   // AmB over KeB
    }
  __syncthreads(); // B2

  f32x4 olacc[4][2];
  #pragma unroll
  for (int m = 0; m < 4; m++)
    #pragma unroll
    for (int nt = 0; nt < 2; nt++) olacc[m][nt] = (f32x4){0.f, 0.f, 0.f, 0.f};
  __builtin_amdgcn_s_setprio(1);
  #pragma unroll
  for (int k0i = 0; k0i < 2; k0i++) {
    int k0 = k0i * 32 + g * 8;
    bf16x8 bfr[2];
    #pragma unroll
    for (int nt = 0; nt < 2; nt++) bfr[nt] = ldsA(SC, 32 * w + 16 * nt + l15, 64, k0);
    #pragma unroll
    for (int m = 0; m < 4; m++) {
      bf16x8 af = ldsA(SB, 16 * m + l15, 64, k0);
      #pragma unroll
      for (int nt = 0; nt < 2; nt++)
        olacc[m][nt] = __builtin_amdgcn_mfma_f32_16x16x32_bf16(af, bfr[nt], olacc[m][nt], 0, 0, 0);
    }
  }
  #pragma unroll
  for (int k0i = 0; k0i < 4; k0i++) {
    int k0 = k0i * 32 + g * 8;
    #pragma unroll
    for (int m = 0; m < 4; m++) {
      bf16x8 af = ldsA(SA, 16 * m + l15, 128, k0);
      #pragma unroll
      for (int nt = 0; nt < 2; nt++)
        olacc[m][nt] = __builtin_amdgcn_mfma_f32_16x16x32_bf16(af, hB[k0i][nt], olacc[m][nt], 0, 0, 0);
    }
  }
  __builtin_amdgcn_s_setprio(0);
  __syncthreads(); // B3

  // ---- phase 2 staging: roped Q -> SA, roped K window -> SB/SC ----
  {
    const short* qg = sqb + qrow;
    const short* kg = skb + (size_t)bkvh * SS * 128 + (ptrdiff_t)(c - 1) * 64 * 128;
    for (int c0 = w * 64; c0 < 1024; c0 += 256) {
      int cc = c0 + l, row = cc >> 4;
      int gb = (cc << 4) ^ ((row & 7) << 4);
      gld_lds16((const short*)((const char*)qg + gb), SA + c0 * 8);
    }
    for (int c0 = w * 64; c0 < 2048; c0 += 256) {
      int cc = c0 + l, row = cc >> 4;
      int gb = (cc << 4) ^ ((row & 7) << 4);
      short* dst = (c0 < 1024) ? (SB + c0 * 8) : (SC + (c0 - 1024) * 8);
      gld_lds16((const short*)((const char*)kg + gb), dst);
    }
  }
  __syncthreads(); // B4

  f32x4 acc[4][2];
  #pragma unroll
  for (int m = 0; m < 4; m++)
    #pragma unroll
    for (int nt = 0; nt < 2; nt++) acc[m][nt] = (f32x4){0.f, 0.f, 0.f, 0.f};
  __builtin_amdgcn_s_setprio(1);
  #pragma unroll
  for (int k0i = 0; k0i < 4; k0i++) {
    int k0 = k0i * 32 + g * 8;
    bf16x8 bfr[2];
    #pragma unroll
    for (int nt = 0; nt < 2; nt++) {
      int row = 32 * w + 16 * nt + l15;
      bfr[nt] = (row < 64) ? ldsA(SB, row, 128, k0) : ldsA(SC, row - 64, 128, k0);
    }
    #pragma unroll
    for (int m = 0; m < 4; m++) {
      bf16x8 af = ldsA(SA, 16 * m + l15, 128, k0);
      #pragma unroll
      for (int nt = 0; nt < 2; nt++)
        acc[m][nt] = __builtin_amdgcn_mfma_f32_16x16x32_bf16(af, bfr[nt], acc[m][nt], 0, 0, 0);
    }
  }
  __builtin_amdgcn_s_setprio(0);

  const float scale = 0.08838834764831845f;
  float mx[4][4];
  #pragma unroll
  for (int m = 0; m < 4; m++)
    #pragma unroll
    for (int r = 0; r < 4; r++) mx[m][r] = -1e30f;
  #pragma unroll
  for (int m = 0; m < 4; m++)
    #pragma unroll
    for (int nt = 0; nt < 2; nt++)
      #pragma unroll
      for (int r = 0; r < 4; r++) {
        int i = 16 * m + 4 * g + r;
        int j = 32 * w + 16 * nt + l15;
        int kp = (c - 1) * 64 + j;
        bool valid = (j >= i) && (j <= i + 64) && (kp >= 0);
        float sc = valid ? acc[m][nt][r] * scale : -1e30f;
        acc[m][nt][r] = sc;
        mx[m][r] = fmaxf(mx[m][r], sc);
      }
  #pragma unroll
  for (int m = 0; m < 4; m++)
    #pragma unroll
    for (int r = 0; r < 4; r++) {
      #pragma unroll
      for (int msk = 1; msk < 16; msk <<= 1) mx[m][r] = fmaxf(mx[m][r], __shfl_xor(mx[m][r], msk));
    }
  if (l15 == 0)
    #pragma unroll
    for (int m = 0; m < 4; m++)
      #pragma unroll
      for (int r = 0; r < 4; r++) wred[0][w][16 * m + 4 * g + r] = mx[m][r];
  __syncthreads(); // B5

  float mrow[4][4], sm[4][4];
  #pragma unroll
  for (int m = 0; m < 4; m++)
    #pragma unroll
    for (int r = 0; r < 4; r++) {
      int i = 16 * m + 4 * g + r;
      mrow[m][r] = fmaxf(fmaxf(wred[0][0][i], wred[0][1][i]), fmaxf(wred[0][2][i], wred[0][3][i]));
      sm[m][r] = 0.f;
    }
  #pragma unroll
  for (int m = 0; m < 4; m++)
    #pragma unroll
    for (int nt = 0; nt < 2; nt++)
      #pragma unroll
      for (int r = 0; r < 4; r++) {
        float p = __expf(acc[m][nt][r] - mrow[m][r]);
        acc[m][nt][r] = p;
        sm[m][r] += p;
      }
  #pragma unroll
  for (int m = 0; m < 4; m++)
    #pragma unroll
    for (int r = 0; r < 4; r++) {
      #pragma unroll
      for (int msk = 1; msk < 16; msk <<= 1) sm[m][r] += __shfl_xor(sm[m][r], msk);
    }
  if (l15 == 0)
    #pragma unroll
    for (int m = 0; m < 4; m++)
      #pragma unroll
      for (int r = 0; r < 4; r++) wred[1][w][16 * m + 4 * g + r] = sm[m][r];
  __syncthreads(); // B6

  #pragma unroll
  for (int m = 0; m < 4; m++)
    #pragma unroll
    for (int r = 0; r < 4; r++) {
      int i = 16 * m + 4 * g + r;
      float s = wred[1][0][i] + wred[1][1][i] + wred[1][2][i] + wred[1][3][i];
      float inv = 1.0f / s;
      #pragma unroll
      for (int nt = 0; nt < 2; nt++) {
        int j = 32 * w + 16 * nt + l15;
        lds_w16_swz(SA, i, 128, j, f2bf(acc[m][nt][r] * inv));
      }
    }
  {
    int j = tid >> 1, dh = (tid & 1) * 64;
    int kp = (c - 1) * 64 + j;
    const short* vrow = vbb + ((size_t)bkvh * SS + kp) * 128 + dh;
    #pragma unroll
    for (int u = 0; u < 8; u++) {
      bf16x8 vv;
      if (kp >= 0) vv = *(const bf16x8*)(vrow + u * 8);
      else vv = (bf16x8){0, 0, 0, 0, 0, 0, 0, 0};
      #pragma unroll
      for (int i2 = 0; i2 < 8; i2++) {
        int row = dh + u * 8 + i2;
        if (row < 64) lds_w16_swz(SB, row, 128, j, vv[i2]);
        else lds_w16_swz(SC, row - 64, 128, j, vv[i2]);
      }
    }
  }
  __syncthreads(); // B7

  f32x4 o[4][2];
  #pragma unroll
  for (int m = 0; m < 4; m++)
    #pragma unroll
    for (int nt = 0; nt < 2; nt++) o[m][nt] = (f32x4){0.f, 0.f, 0.f, 0.f};
  __builtin_amdgcn_s_setprio(1);
  #pragma unroll
  for (int k0i = 0; k0i < 4; k0i++) {
    int k0 = k0i * 32 + g * 8;
    bf16x8 bfr[2];
    #pragma unroll
    for (int nt = 0; nt < 2; nt++) {
      int row = 32 * w + 16 * nt + l15;
      bfr[nt] = (row < 64) ? ldsA(SB, row, 128, k0) : ldsA(SC, row - 64, 128, k0);
    }
    #pragma unroll
    for (int m = 0; m < 4; m++) {
      bf16x8 af = ldsA(SA, 16 * m + l15, 128, k0);
      #pragma unroll
      for (int nt = 0; nt < 2; nt++)
        o[m][nt] = __builtin_amdgcn_mfma_f32_16x16x32_bf16(af, bfr[nt], o[m][nt], 0, 0, 0);
    }
  }
  __builtin_amdgcn_s_setprio(0);
  #pragma unroll
  for (int m = 0; m < 4; m++)
    #pragma unroll
    for (int nt = 0; nt < 2; nt++)
      #pragma unroll
      for (int r = 0; r < 4; r++) {
        int i = 16 * m + 4 * g + r, d = 32 * w + 16 * nt + l15;
        float val = 0.5f * o[m][nt][r] + 0.5f * olacc[m][nt][r];
        obf[((size_t)(b * SS + c * 64 + i)) * HIDN + hq * 128 + d] = f2bf(val);
      }
}

// --------------------------------------------------------------------------
extern "C" void kernel_launch(void* const* d_in, const int* in_sizes, int n_in,
                              void* d_out, int out_size, void* d_ws, size_t ws_size,
                              hipStream_t stream)
{
  const float* hs = (const float*)d_in[0];
  const int*  pos = (const int*)d_in[1];
  const float* Wq = (const float*)d_in[2];
  const float* bq = (const float*)d_in[3];
  const float* Wk = (const float*)d_in[4];
  const float* bk = (const float*)d_in[5];
  const float* Wv = (const float*)d_in[6];
  const float* bv = (const float*)d_in[7];
  const float* Wo = (const float*)d_in[8];
  float* out = (float*)d_out;

  float* w = (float*)d_ws;
  const size_t QSZ = (size_t)BB * HH * SS * DD;         // 8388608
  const size_t KSZ = (size_t)BB * HKVV * SS * DD;       // 2097152
  const size_t TSZ = (size_t)BB * HKVV * NCH * DD * DD; // 4194304
  short* hs_bf = (short*)w; w += QSZ / 2;
  float* qbuf  = w; w += QSZ;
  float* kbuf  = w; w += KSZ;
  short* qsm   = (short*)w; w += QSZ / 2;
  short* sqb   = (short*)w; w += QSZ / 2;
  short* ksm   = (short*)w; w += KSZ / 2;
  short* skb   = (short*)w; w += KSZ / 2;
  short* vb    = (short*)w; w += KSZ / 2;
  float* gbuf  = w; w += KSZ;
  float* Gc    = w; w += KSZ;
  float* Tc    = w; w += TSZ;             // bf16 TcB in front half; obf aliases after passB
  short* hT    = (short*)w; w += TSZ / 2;
  float* ct    = w; w += (size_t)SS * 64;
  float* st    = w; w += (size_t)SS * 64;
  short* wo_bf = (short*)w; w += (size_t)HIDN * HIDN / 2;
  short* wqkv_bf = (short*)w; w += (size_t)3072 * HIDN / 2;

  short* TcB = (short*)Tc;
  short* obf = (short*)Tc;

  dim3 blk(256);
  const int M = BB * SS; // 4096

  cast_all_k<<<dim3(18944), blk, 0, stream>>>(hs, Wq, Wk, Wv, Wo, pos,
                                              hs_bf, wqkv_bf, wo_bf, ct, st);

  qkv_gemm_k<<<dim3(768), blk, 0, stream>>>(hs_bf, wqkv_bf, bq, bk, bv,
                                            qbuf, kbuf, vb);

  prep_k<<<dim3((BB * HH * SS + BB * HKVV * SS) / 8), blk, 0, stream>>>(
      qbuf, kbuf, ct, st, qsm, sqb, ksm, skb, gbuf);

  gla_passA_k<<<dim3(BB * HKVV * NCH), blk, 0, stream>>>(ksm, vb, gbuf, Gc, TcB);
  gla_passB_k<<<dim3(BB * HKVV * DD * DD / 256), blk, 0, stream>>>(TcB, Gc, hT);

  gla_win_k<<<dim3(BB * HH * NCH), blk, 0, stream>>>(qsm, ksm, sqb, skb, vb, Gc, hT, obf);

  mfma_gemm_bt<<<dim3(512), blk, 0, stream>>>(obf, wo_bf, out, M, HIDN, HIDN);
}